// Round 2
// baseline (2078.933 us; speedup 1.0000x reference)
//
#include <hip/hip_runtime.h>
#include <math.h>

// Problem constants (fixed instance: B=2, S=2048, D=1024, H=16)
constexpr int B  = 2;
constexpr int S  = 2048;
constexpr int D  = 1024;
constexpr int H  = 16;
constexpr int HD = 64;                    // head dim = D/H
constexpr float SCALE = 0.125f;           // 1/sqrt(HD)
constexpr float SINK_STRENGTH = 0.1f;

// ---------------------------------------------------------------------------
// Kernel 1: per-batch sink index = argmin over valid (mask!=0) positions,
// first-occurrence tie-break (matches jnp.argmin). Also writes the index as
// float into the output tail (tuple output is concatenated flat; float
// interpretation per harness contract "else float*"). Tail write is guarded
// by out_size to avoid OOB if the harness sizes d_out as B*S*D only.
// ---------------------------------------------------------------------------
__global__ void sink_kernel(const float* __restrict__ pos,
                            const int* __restrict__ mask,
                            int* __restrict__ sink_idx,
                            float* __restrict__ out_tail, int tail_elems) {
  const int b = blockIdx.x;
  __shared__ float sval[256];
  __shared__ int   sidx[256];
  float best = INFINITY;
  int   bidx = 0x7fffffff;
  for (int i = threadIdx.x; i < S; i += 256) {
    float v = (mask[b * S + i] == 0) ? INFINITY : pos[b * S + i];
    if (v < best || (v == best && i < bidx)) { best = v; bidx = i; }
  }
  sval[threadIdx.x] = best;
  sidx[threadIdx.x] = bidx;
  __syncthreads();
  for (int off = 128; off > 0; off >>= 1) {
    if ((int)threadIdx.x < off) {
      float v  = sval[threadIdx.x + off];
      int   ix = sidx[threadIdx.x + off];
      if (v < sval[threadIdx.x] ||
          (v == sval[threadIdx.x] && ix < sidx[threadIdx.x])) {
        sval[threadIdx.x] = v;
        sidx[threadIdx.x] = ix;
      }
    }
    __syncthreads();
  }
  if (threadIdx.x == 0) {
    sink_idx[b] = sidx[0];
    if (b < tail_elems) out_tail[b] = (float)sidx[0];
  }
}

// ---------------------------------------------------------------------------
// Kernel 2: Y[m,n] = sum_k X[m,k] * W[n,k] + bias[n]   (i.e. X @ W^T + b)
// 64x64 tile, BK=16, 256 threads, 4x4 micro-tile per thread, fp32.
// Both X and W are K-major so both tile loads are coalesced float4 rows.
// ---------------------------------------------------------------------------
constexpr int BM = 64, BN = 64, BK = 16;

__global__ __launch_bounds__(256) void gemm_bias_kernel(
    const float* __restrict__ X,    // [M,K]
    const float* __restrict__ W,    // [N,K]
    const float* __restrict__ bias, // [N]
    float* __restrict__ Y,          // [M,N]
    int M, int N, int K) {
  __shared__ float Xs[BK][BM];  // [k][m]
  __shared__ float Ws[BK][BN];  // [k][n]
  const int tid = threadIdx.x;
  const int tx = tid & 15, ty = tid >> 4;
  const int m0 = blockIdx.y * BM, n0 = blockIdx.x * BN;

  float acc[4][4] = {};

  const int lrow = tid >> 2;        // 0..63
  const int lk   = (tid & 3) << 2;  // 0,4,8,12

  for (int k0 = 0; k0 < K; k0 += BK) {
    float4 xv = *reinterpret_cast<const float4*>(
        &X[(size_t)(m0 + lrow) * K + k0 + lk]);
    float4 wv = *reinterpret_cast<const float4*>(
        &W[(size_t)(n0 + lrow) * K + k0 + lk]);
    Xs[lk + 0][lrow] = xv.x; Xs[lk + 1][lrow] = xv.y;
    Xs[lk + 2][lrow] = xv.z; Xs[lk + 3][lrow] = xv.w;
    Ws[lk + 0][lrow] = wv.x; Ws[lk + 1][lrow] = wv.y;
    Ws[lk + 2][lrow] = wv.z; Ws[lk + 3][lrow] = wv.w;
    __syncthreads();
#pragma unroll
    for (int kk = 0; kk < BK; ++kk) {
      float a[4], w[4];
#pragma unroll
      for (int i = 0; i < 4; ++i) a[i] = Xs[kk][ty * 4 + i];
#pragma unroll
      for (int j = 0; j < 4; ++j) w[j] = Ws[kk][tx * 4 + j];
#pragma unroll
      for (int i = 0; i < 4; ++i)
#pragma unroll
        for (int j = 0; j < 4; ++j)
          acc[i][j] = fmaf(a[i], w[j], acc[i][j]);
    }
    __syncthreads();
  }

#pragma unroll
  for (int i = 0; i < 4; ++i) {
    float4 r;
    r.x = acc[i][0] + bias[n0 + tx * 4 + 0];
    r.y = acc[i][1] + bias[n0 + tx * 4 + 1];
    r.z = acc[i][2] + bias[n0 + tx * 4 + 2];
    r.w = acc[i][3] + bias[n0 + tx * 4 + 3];
    *reinterpret_cast<float4*>(
        &Y[(size_t)(m0 + ty * 4 + i) * N + n0 + tx * 4]) = r;
  }
}

// ---------------------------------------------------------------------------
// Kernel 3: flash-style attention, fp32.
// Grid (S/BQ, H, B), 256 threads. Per block: 64 q-rows of one (b,h).
// Q and K staged TRANSPOSED in LDS ([d][row]) so the QK^T inner loop reads
// both operands as conflict-free ds_read_b128 along the row dimension.
// P tile reuses the K LDS buffer. Online softmax with sink bias + key mask.
// ---------------------------------------------------------------------------
constexpr int BQ = 64, BKV = 64;

__global__ __launch_bounds__(256) void attn_kernel(
    const float* __restrict__ qg, const float* __restrict__ kg,
    const float* __restrict__ vg, const int* __restrict__ mask,
    const int* __restrict__ sink_idx, float* __restrict__ og) {
  __shared__ float QsT[HD][BQ + 4];   // [d][qrow]
  __shared__ float KsT[HD][BKV + 4];  // [d][kcol]; reused as Ps[BQ][BKV+4]
  __shared__ float Vs[BKV][HD + 4];   // [kcol][d]
  float (*Ps)[BKV + 4] = reinterpret_cast<float (*)[BKV + 4]>(KsT);

  const int b = blockIdx.z, h = blockIdx.y, q0 = blockIdx.x * BQ;
  const int tid = threadIdx.x;
  const int tx = tid & 15, ty = tid >> 4;
  const int sb = sink_idx[b];

  // Load Q tile (transposed into LDS). Coalesced float4 global reads.
  for (int e = tid; e < BQ * (HD / 4); e += 256) {
    int r  = e >> 4;
    int dq = (e & 15) << 2;
    float4 qv = *reinterpret_cast<const float4*>(
        &qg[((size_t)b * S + q0 + r) * D + h * HD + dq]);
    QsT[dq + 0][r] = qv.x; QsT[dq + 1][r] = qv.y;
    QsT[dq + 2][r] = qv.z; QsT[dq + 3][r] = qv.w;
  }

  float m_i[4], l_i[4];
  float acc[4][4] = {};
#pragma unroll
  for (int i = 0; i < 4; ++i) { m_i[i] = -INFINITY; l_i[i] = 0.f; }

  for (int kv0 = 0; kv0 < S; kv0 += BKV) {
    __syncthreads();  // prev PV reads done (also fences the Q-tile write)
    // Load K (transposed) and V tiles.
    for (int e = tid; e < BKV * (HD / 4); e += 256) {
      int r  = e >> 4;
      int dq = (e & 15) << 2;
      float4 kv = *reinterpret_cast<const float4*>(
          &kg[((size_t)b * S + kv0 + r) * D + h * HD + dq]);
      KsT[dq + 0][r] = kv.x; KsT[dq + 1][r] = kv.y;
      KsT[dq + 2][r] = kv.z; KsT[dq + 3][r] = kv.w;
      *reinterpret_cast<float4*>(&Vs[r][dq]) =
          *reinterpret_cast<const float4*>(
              &vg[((size_t)b * S + kv0 + r) * D + h * HD + dq]);
    }
    __syncthreads();

    // Scores: sc[i][j] = q_row(ty*4+i) . k_col(tx*4+j)
    float sc[4][4] = {};
#pragma unroll
    for (int dd = 0; dd < HD; ++dd) {
      float4 a  = *reinterpret_cast<const float4*>(&QsT[dd][ty * 4]);
      float4 bb = *reinterpret_cast<const float4*>(&KsT[dd][tx * 4]);
      float av[4] = {a.x, a.y, a.z, a.w};
      float bv[4] = {bb.x, bb.y, bb.z, bb.w};
#pragma unroll
      for (int i = 0; i < 4; ++i)
#pragma unroll
        for (int j = 0; j < 4; ++j)
          sc[i][j] = fmaf(av[i], bv[j], sc[i][j]);
    }

    // scale + sink bias + key-side mask (mask overrides to exactly -1e9)
    float colb[4];
    int   valid[4];
#pragma unroll
    for (int j = 0; j < 4; ++j) {
      int col  = kv0 + tx * 4 + j;
      valid[j] = mask[b * S + col];
      colb[j]  = (col == sb) ? SINK_STRENGTH : 0.f;
    }
#pragma unroll
    for (int i = 0; i < 4; ++i)
#pragma unroll
      for (int j = 0; j < 4; ++j)
        sc[i][j] = valid[j] ? fmaf(sc[i][j], SCALE, colb[j]) : -1e9f;

    // Online softmax. Row groups = 16 lanes (tx); butterfly reduce.
    float mx[4];
#pragma unroll
    for (int i = 0; i < 4; ++i)
      mx[i] = fmaxf(fmaxf(sc[i][0], sc[i][1]), fmaxf(sc[i][2], sc[i][3]));
#pragma unroll
    for (int off = 1; off < 16; off <<= 1)
#pragma unroll
      for (int i = 0; i < 4; ++i)
        mx[i] = fmaxf(mx[i], __shfl_xor(mx[i], off, 64));

    float p[4][4];
    float rs[4];
#pragma unroll
    for (int i = 0; i < 4; ++i) {
      float mn   = fmaxf(m_i[i], mx[i]);
      float corr = __expf(m_i[i] - mn);  // 0 on first tile (m_i=-inf)
#pragma unroll
      for (int j = 0; j < 4; ++j) p[i][j] = __expf(sc[i][j] - mn);
      rs[i] = (p[i][0] + p[i][1]) + (p[i][2] + p[i][3]);
      m_i[i] = mn;
      l_i[i] *= corr;
#pragma unroll
      for (int j = 0; j < 4; ++j) acc[i][j] *= corr;
    }
#pragma unroll
    for (int off = 1; off < 16; off <<= 1)
#pragma unroll
      for (int i = 0; i < 4; ++i) rs[i] += __shfl_xor(rs[i], off, 64);
#pragma unroll
    for (int i = 0; i < 4; ++i) l_i[i] += rs[i];

    // Publish P tile (reusing KsT storage), then PV.
    __syncthreads();  // all KsT (scores) reads complete before overwrite
#pragma unroll
    for (int i = 0; i < 4; ++i) {
      float4 pv4 = make_float4(p[i][0], p[i][1], p[i][2], p[i][3]);
      *reinterpret_cast<float4*>(&Ps[ty * 4 + i][tx * 4]) = pv4;
    }
    __syncthreads();

#pragma unroll
    for (int c4 = 0; c4 < BKV; c4 += 4) {
      float4 pp[4];
#pragma unroll
      for (int i = 0; i < 4; ++i)
        pp[i] = *reinterpret_cast<const float4*>(&Ps[ty * 4 + i][c4]);
#pragma unroll
      for (int cc = 0; cc < 4; ++cc) {
        float4 vv = *reinterpret_cast<const float4*>(&Vs[c4 + cc][tx * 4]);
        float vvv[4] = {vv.x, vv.y, vv.z, vv.w};
        float pc[4];
#pragma unroll
        for (int i = 0; i < 4; ++i)
          pc[i] = (cc == 0) ? pp[i].x
                : (cc == 1) ? pp[i].y
                : (cc == 2) ? pp[i].z
                            : pp[i].w;
#pragma unroll
        for (int i = 0; i < 4; ++i)
#pragma unroll
          for (int j = 0; j < 4; ++j)
            acc[i][j] = fmaf(pc[i], vvv[j], acc[i][j]);
      }
    }
  }

  // Normalize and store [B,S,D]-layout head output.
#pragma unroll
  for (int i = 0; i < 4; ++i) {
    float inv = 1.0f / l_i[i];
    float4 r;
    r.x = acc[i][0] * inv;
    r.y = acc[i][1] * inv;
    r.z = acc[i][2] * inv;
    r.w = acc[i][3] * inv;
    *reinterpret_cast<float4*>(
        &og[((size_t)b * S + q0 + ty * 4 + i) * D + h * HD + tx * 4]) = r;
  }
}

// ---------------------------------------------------------------------------
// Launch: sink -> Q/K/V projections -> attention -> output projection.
// Workspace layout (fp32): q | k | v | attn_out | sink_idx(int[B])
// = 4 * B*S*D * 4B + 8B  ~= 67.1 MB.
// ---------------------------------------------------------------------------
extern "C" void kernel_launch(void* const* d_in, const int* in_sizes, int n_in,
                              void* d_out, int out_size, void* d_ws,
                              size_t ws_size, hipStream_t stream) {
  const float* query = (const float*)d_in[0];
  const float* key_  = (const float*)d_in[1];
  const float* value = (const float*)d_in[2];
  const float* pos   = (const float*)d_in[3];
  const int*   amask = (const int*)d_in[4];
  const float* Wq = (const float*)d_in[5];
  const float* bq = (const float*)d_in[6];
  const float* Wk = (const float*)d_in[7];
  const float* bk = (const float*)d_in[8];
  const float* Wv = (const float*)d_in[9];
  const float* bv = (const float*)d_in[10];
  const float* Wo = (const float*)d_in[11];
  const float* bo = (const float*)d_in[12];
  float* out = (float*)d_out;

  float* qp = (float*)d_ws;
  float* kp = qp + (size_t)B * S * D;
  float* vp = kp + (size_t)B * S * D;
  float* ap = vp + (size_t)B * S * D;
  int* sidx = (int*)(ap + (size_t)B * S * D);

  const int tail_elems = out_size - B * S * D;  // sink-index slots in d_out
  sink_kernel<<<B, 256, 0, stream>>>(pos, amask, sidx,
                                     out + (size_t)B * S * D, tail_elems);

  dim3 blk(256);
  dim3 gproj(D / BN, (B * S) / BM);
  gemm_bias_kernel<<<gproj, blk, 0, stream>>>(query, Wq, bq, qp, B * S, D, D);
  gemm_bias_kernel<<<gproj, blk, 0, stream>>>(key_, Wk, bk, kp, B * S, D, D);
  gemm_bias_kernel<<<gproj, blk, 0, stream>>>(value, Wv, bv, vp, B * S, D, D);

  attn_kernel<<<dim3(S / BQ, H, B), blk, 0, stream>>>(qp, kp, vp, amask,
                                                      sidx, ap);

  gemm_bias_kernel<<<gproj, blk, 0, stream>>>(ap, Wo, bo, out, B * S, D, D);
}

// Round 3
// 728.940 us; speedup vs baseline: 2.8520x; 2.8520x over previous
//
#include <hip/hip_runtime.h>
#include <hip/hip_bf16.h>
#include <math.h>

// Problem constants (fixed instance: B=2, S=2048, D=1024, H=16)
constexpr int B  = 2;
constexpr int S  = 2048;
constexpr int D  = 1024;
constexpr int H  = 16;
constexpr int HD = 64;                    // head dim = D/H
constexpr float SCALE = 0.125f;           // 1/sqrt(HD)
constexpr float SINK_STRENGTH = 0.1f;

typedef short v4s __attribute__((ext_vector_type(4)));
typedef short v8s __attribute__((ext_vector_type(8)));
typedef float v4f __attribute__((ext_vector_type(4)));

// ---------------------------------------------------------------------------
// MFMA wrappers
// ---------------------------------------------------------------------------
__device__ inline v4f mfma_16x16x32_bf16(v8s a, v8s b, v4f c) {
  return __builtin_amdgcn_mfma_f32_16x16x32_bf16(a, b, c, 0, 0, 0);
}

__device__ inline v4f mfma_16x16x16_bf16(v4s a, v4s b, v4f c) {
#if defined(__has_builtin)
#if __has_builtin(__builtin_amdgcn_mfma_f32_16x16x16bf16_1k)
  return __builtin_amdgcn_mfma_f32_16x16x16bf16_1k(a, b, c, 0, 0, 0);
#define MFMA16_DONE 1
#endif
#endif
#ifndef MFMA16_DONE
  v4f d;
  asm volatile("v_mfma_f32_16x16x16_bf16 %0, %1, %2, %3"
               : "=v"(d) : "v"(a), "v"(b), "v"(c));
  return d;
#endif
}

__device__ inline unsigned short f2bf(float f) {
  __hip_bfloat16 h = __float2bfloat16(f);  // RNE
  return *reinterpret_cast<unsigned short*>(&h);
}

// ---------------------------------------------------------------------------
// Kernel 1: per-batch sink index = argmin over valid (mask!=0) positions,
// first-occurrence tie-break (matches jnp.argmin). Tail write guarded.
// ---------------------------------------------------------------------------
__global__ void sink_kernel(const float* __restrict__ pos,
                            const int* __restrict__ mask,
                            int* __restrict__ sink_idx,
                            float* __restrict__ out_tail, int tail_elems) {
  const int b = blockIdx.x;
  __shared__ float sval[256];
  __shared__ int   sidx[256];
  float best = INFINITY;
  int   bidx = 0x7fffffff;
  for (int i = threadIdx.x; i < S; i += 256) {
    float v = (mask[b * S + i] == 0) ? INFINITY : pos[b * S + i];
    if (v < best || (v == best && i < bidx)) { best = v; bidx = i; }
  }
  sval[threadIdx.x] = best;
  sidx[threadIdx.x] = bidx;
  __syncthreads();
  for (int off = 128; off > 0; off >>= 1) {
    if ((int)threadIdx.x < off) {
      float v  = sval[threadIdx.x + off];
      int   ix = sidx[threadIdx.x + off];
      if (v < sval[threadIdx.x] ||
          (v == sval[threadIdx.x] && ix < sidx[threadIdx.x])) {
        sval[threadIdx.x] = v;
        sidx[threadIdx.x] = ix;
      }
    }
    __syncthreads();
  }
  if (threadIdx.x == 0) {
    sink_idx[b] = sidx[0];
    if (b < tail_elems) out_tail[b] = (float)sidx[0];
  }
}

// ---------------------------------------------------------------------------
// Kernel 2: fp32 GEMM  Y = X @ W^T + b  (unchanged this round)
// ---------------------------------------------------------------------------
constexpr int BM = 64, BN = 64, BK = 16;

__global__ __launch_bounds__(256) void gemm_bias_kernel(
    const float* __restrict__ X, const float* __restrict__ W,
    const float* __restrict__ bias, float* __restrict__ Y,
    int M, int N, int K) {
  __shared__ float Xs[BK][BM];
  __shared__ float Ws[BK][BN];
  const int tid = threadIdx.x;
  const int tx = tid & 15, ty = tid >> 4;
  const int m0 = blockIdx.y * BM, n0 = blockIdx.x * BN;

  float acc[4][4] = {};
  const int lrow = tid >> 2;
  const int lk   = (tid & 3) << 2;

  for (int k0 = 0; k0 < K; k0 += BK) {
    float4 xv = *reinterpret_cast<const float4*>(
        &X[(size_t)(m0 + lrow) * K + k0 + lk]);
    float4 wv = *reinterpret_cast<const float4*>(
        &W[(size_t)(n0 + lrow) * K + k0 + lk]);
    Xs[lk + 0][lrow] = xv.x; Xs[lk + 1][lrow] = xv.y;
    Xs[lk + 2][lrow] = xv.z; Xs[lk + 3][lrow] = xv.w;
    Ws[lk + 0][lrow] = wv.x; Ws[lk + 1][lrow] = wv.y;
    Ws[lk + 2][lrow] = wv.z; Ws[lk + 3][lrow] = wv.w;
    __syncthreads();
#pragma unroll
    for (int kk = 0; kk < BK; ++kk) {
      float a[4], w[4];
#pragma unroll
      for (int i = 0; i < 4; ++i) a[i] = Xs[kk][ty * 4 + i];
#pragma unroll
      for (int j = 0; j < 4; ++j) w[j] = Ws[kk][tx * 4 + j];
#pragma unroll
      for (int i = 0; i < 4; ++i)
#pragma unroll
        for (int j = 0; j < 4; ++j)
          acc[i][j] = fmaf(a[i], w[j], acc[i][j]);
    }
    __syncthreads();
  }

#pragma unroll
  for (int i = 0; i < 4; ++i) {
    float4 r;
    r.x = acc[i][0] + bias[n0 + tx * 4 + 0];
    r.y = acc[i][1] + bias[n0 + tx * 4 + 1];
    r.z = acc[i][2] + bias[n0 + tx * 4 + 2];
    r.w = acc[i][3] + bias[n0 + tx * 4 + 3];
    *reinterpret_cast<float4*>(
        &Y[(size_t)(m0 + ty * 4 + i) * N + n0 + tx * 4]) = r;
  }
}

// ---------------------------------------------------------------------------
// Kernel 3: flash attention, bf16 MFMA, swapped-operand layout.
//
// Block = 4 waves; wave w owns q-rows [q0 + w*16, +16). Per 64-kv tile:
//   S^T(64kv x 16q) = mfma_16x16x32(A=K-frag, B=Q-frag) x 8
//     -> lane owns q = lane&15; 16 scores at kv = t*16 + (lane>>4)*4 + r
//   online softmax: in-lane over 16 + shfl_xor(16,32)  (lane-scalar m,l)
//   O^T(64d x 16q) += mfma_16x16x16(A=V^T-frag, B=P^T D-frag) x 16
// LDS (bf16, XOR-swizzled byte ^= (row&7)<<4): Qs[64][64], Ks[64][64],
// VsT[64][64] (rows=d, cols=kv), sbias[64] f32 (mask/sink pre-merged).
// ---------------------------------------------------------------------------
constexpr int BQ = 64, BKV = 64;

__device__ inline unsigned swz(int row, int bytecol) {
  return (unsigned)(row * 128 + (bytecol ^ ((row & 7) << 4)));
}

__global__ __launch_bounds__(256) void attn_kernel(
    const float* __restrict__ qg, const float* __restrict__ kg,
    const float* __restrict__ vg, const int* __restrict__ mask,
    const int* __restrict__ sink_idx, float* __restrict__ og) {
  __shared__ __align__(16) unsigned char smem[3 * 64 * 128 + 256];
  unsigned char* Qs  = smem;                 // [64 q][64 d] bf16, swizzled
  unsigned char* Ks  = smem + 8192;          // [64 kv][64 d] bf16, swizzled
  unsigned char* VsT = smem + 16384;         // [64 d][64 kv] bf16, swizzled
  float* sbias = reinterpret_cast<float*>(smem + 24576);  // [64 kv]

  const int b = blockIdx.z, h = blockIdx.y, q0 = blockIdx.x * BQ;
  const int tid  = threadIdx.x;
  const int lane = tid & 63, wv = tid >> 6;
  const int lr = lane & 15, g = lane >> 4;
  const int sb = sink_idx[b];

  // ---- stage Q tile (once): thread t -> row q=t>>2, 16 cols at (t&3)*16
  {
    const int qr = tid >> 2, cb = tid & 3;
    const float* src = qg + ((size_t)b * S + q0 + qr) * D + h * HD + cb * 16;
#pragma unroll
    for (int u = 0; u < 4; ++u) {
      float4 f = *reinterpret_cast<const float4*>(src + u * 4);
      ushort4 h4 = make_ushort4(f2bf(f.x), f2bf(f.y), f2bf(f.z), f2bf(f.w));
      *reinterpret_cast<ushort4*>(Qs + swz(qr, cb * 32 + u * 8)) = h4;
    }
  }

  float m_i = -INFINITY, l_i = 0.f;
  v4f acc[4] = {};  // O^T frags: acc[c] covers d = c*16 + g*4 + r, q = lr

  for (int kv0 = 0; kv0 < S; kv0 += BKV) {
    __syncthreads();  // previous tile's LDS reads done (also fences Q stage)

    // ---- stage K tile: row kv=t>>2, 16 cols at (t&3)*16
    {
      const int kr = tid >> 2, cb = tid & 3;
      const float* src =
          kg + ((size_t)b * S + kv0 + kr) * D + h * HD + cb * 16;
#pragma unroll
      for (int u = 0; u < 4; ++u) {
        float4 f = *reinterpret_cast<const float4*>(src + u * 4);
        ushort4 h4 = make_ushort4(f2bf(f.x), f2bf(f.y), f2bf(f.z), f2bf(f.w));
        *reinterpret_cast<ushort4*>(Ks + swz(kr, cb * 32 + u * 8)) = h4;
      }
    }
    // ---- stage V^T tile: thread t does a 4x4 transpose.
    // reads V[kv0+kvl+i][d0..d0+3], writes VsT[d0+c][kvl..kvl+3]
    {
      const int kvl = (tid >> 4) * 4, d0 = (tid & 15) * 4;
      float4 fr[4];
#pragma unroll
      for (int i = 0; i < 4; ++i)
        fr[i] = *reinterpret_cast<const float4*>(
            vg + ((size_t)b * S + kv0 + kvl + i) * D + h * HD + d0);
      const float* fc = reinterpret_cast<const float*>(fr);
#pragma unroll
      for (int c = 0; c < 4; ++c) {
        ushort4 h4 = make_ushort4(f2bf(fc[0 * 4 + c]), f2bf(fc[1 * 4 + c]),
                                  f2bf(fc[2 * 4 + c]), f2bf(fc[3 * 4 + c]));
        *reinterpret_cast<ushort4*>(VsT + swz(d0 + c, kvl * 2)) = h4;
      }
    }
    // ---- stage merged mask/sink bias per kv column
    if (tid < BKV) {
      const int kv = kv0 + tid;
      sbias[tid] =
          mask[b * S + kv] ? ((kv == sb) ? SINK_STRENGTH : 0.f) : -1e9f;
    }
    __syncthreads();

    // ---- QK^T (swapped): st[t] = S^T rows [t*16, t*16+16), cols = q
    v4f st[4] = {};
#pragma unroll
    for (int t = 0; t < 4; ++t) {
#pragma unroll
      for (int ks = 0; ks < 2; ++ks) {
        v8s aK = *reinterpret_cast<const v8s*>(
            Ks + swz(t * 16 + lr, ks * 64 + g * 16));
        v8s bQ = *reinterpret_cast<const v8s*>(
            Qs + swz(wv * 16 + lr, ks * 64 + g * 16));
        st[t] = mfma_16x16x32_bf16(aK, bQ, st[t]);
      }
    }

    // ---- scale + bias, online softmax (lane-scalar: this lane's q = lr)
    float s[4][4];
    float mx = -INFINITY;
#pragma unroll
    for (int t = 0; t < 4; ++t) {
      float4 b4 = *reinterpret_cast<const float4*>(&sbias[t * 16 + g * 4]);
      const float bb[4] = {b4.x, b4.y, b4.z, b4.w};
#pragma unroll
      for (int r = 0; r < 4; ++r) {
        s[t][r] = fmaf(st[t][r], SCALE, bb[r]);
        mx = fmaxf(mx, s[t][r]);
      }
    }
    mx = fmaxf(mx, __shfl_xor(mx, 16, 64));
    mx = fmaxf(mx, __shfl_xor(mx, 32, 64));

    const float mn   = fmaxf(m_i, mx);
    const float corr = __expf(m_i - mn);  // exp(-inf)=0 on first tile
    float rs = 0.f;
    v4s pb[4];
#pragma unroll
    for (int t = 0; t < 4; ++t) {
#pragma unroll
      for (int r = 0; r < 4; ++r) {
        float pv = __expf(s[t][r] - mn);
        rs += pv;
        pb[t][r] = (short)f2bf(pv);
      }
    }
    rs += __shfl_xor(rs, 16, 64);
    rs += __shfl_xor(rs, 32, 64);
    l_i = l_i * corr + rs;
    m_i = mn;
#pragma unroll
    for (int c = 0; c < 4; ++c) acc[c] = acc[c] * corr;

    // ---- PV: O^T += V^T-chunk(16d x 16kv) @ P^T-chunk(16kv x 16q)
#pragma unroll
    for (int t = 0; t < 4; ++t) {
#pragma unroll
      for (int c = 0; c < 4; ++c) {
        v4s aV = *reinterpret_cast<const v4s*>(
            VsT + swz(c * 16 + lr, t * 32 + g * 8));
        acc[c] = mfma_16x16x16_bf16(aV, pb[t], acc[c]);
      }
    }
  }

  // ---- epilogue: O[q][d] = O^T/l ; acc[c] reg r -> d = c*16 + g*4 + r
  const float inv = 1.0f / l_i;
  float* orow = og + ((size_t)b * S + q0 + wv * 16 + lr) * D + h * HD;
#pragma unroll
  for (int c = 0; c < 4; ++c) {
    v4f r = acc[c] * inv;
    *reinterpret_cast<v4f*>(orow + c * 16 + g * 4) = r;
  }
}

// ---------------------------------------------------------------------------
// Launch: sink -> Q/K/V projections (fp32) -> bf16 MFMA attention -> O proj.
// Workspace: q | k | v | attn_out (fp32) | sink_idx(int[B])
// ---------------------------------------------------------------------------
extern "C" void kernel_launch(void* const* d_in, const int* in_sizes, int n_in,
                              void* d_out, int out_size, void* d_ws,
                              size_t ws_size, hipStream_t stream) {
  const float* query = (const float*)d_in[0];
  const float* key_  = (const float*)d_in[1];
  const float* value = (const float*)d_in[2];
  const float* pos   = (const float*)d_in[3];
  const int*   amask = (const int*)d_in[4];
  const float* Wq = (const float*)d_in[5];
  const float* bq = (const float*)d_in[6];
  const float* Wk = (const float*)d_in[7];
  const float* bk = (const float*)d_in[8];
  const float* Wv = (const float*)d_in[9];
  const float* bv = (const float*)d_in[10];
  const float* Wo = (const float*)d_in[11];
  const float* bo = (const float*)d_in[12];
  float* out = (float*)d_out;

  float* qp = (float*)d_ws;
  float* kp = qp + (size_t)B * S * D;
  float* vp = kp + (size_t)B * S * D;
  float* ap = vp + (size_t)B * S * D;
  int* sidx = (int*)(ap + (size_t)B * S * D);

  const int tail_elems = out_size - B * S * D;
  sink_kernel<<<B, 256, 0, stream>>>(pos, amask, sidx,
                                     out + (size_t)B * S * D, tail_elems);

  dim3 blk(256);
  dim3 gproj(D / BN, (B * S) / BM);
  gemm_bias_kernel<<<gproj, blk, 0, stream>>>(query, Wq, bq, qp, B * S, D, D);
  gemm_bias_kernel<<<gproj, blk, 0, stream>>>(key_, Wk, bk, kp, B * S, D, D);
  gemm_bias_kernel<<<gproj, blk, 0, stream>>>(value, Wv, bv, vp, B * S, D, D);

  attn_kernel<<<dim3(S / BQ, H, B), blk, 0, stream>>>(qp, kp, vp, amask,
                                                      sidx, ap);

  gemm_bias_kernel<<<gproj, blk, 0, stream>>>(ap, Wo, bo, out, B * S, D, D);
}

// Round 5
// 350.691 us; speedup vs baseline: 5.9281x; 2.0786x over previous
//
#include <hip/hip_runtime.h>
#include <hip/hip_bf16.h>
#include <math.h>

// Problem constants (fixed instance: B=2, S=2048, D=1024, H=16)
constexpr int B  = 2;
constexpr int S  = 2048;
constexpr int D  = 1024;
constexpr int H  = 16;
constexpr int HD = 64;                    // head dim = D/H
constexpr float SCALE = 0.125f;           // 1/sqrt(HD)
constexpr float SINK_STRENGTH = 0.1f;

typedef short v4s __attribute__((ext_vector_type(4)));
typedef short v8s __attribute__((ext_vector_type(8)));
typedef float v4f __attribute__((ext_vector_type(4)));

// ---------------------------------------------------------------------------
// MFMA wrappers
// ---------------------------------------------------------------------------
__device__ inline v4f mfma_16x16x32_bf16(v8s a, v8s b, v4f c) {
  return __builtin_amdgcn_mfma_f32_16x16x32_bf16(a, b, c, 0, 0, 0);
}

__device__ inline v4f mfma_16x16x16_bf16(v4s a, v4s b, v4f c) {
#if defined(__has_builtin)
#if __has_builtin(__builtin_amdgcn_mfma_f32_16x16x16bf16_1k)
  return __builtin_amdgcn_mfma_f32_16x16x16bf16_1k(a, b, c, 0, 0, 0);
#define MFMA16_DONE 1
#endif
#endif
#ifndef MFMA16_DONE
  v4f d;
  asm volatile("v_mfma_f32_16x16x16_bf16 %0, %1, %2, %3"
               : "=v"(d) : "v"(a), "v"(b), "v"(c));
  return d;
#endif
}

__device__ inline unsigned short f2bf(float f) {
  __hip_bfloat16 h = __float2bfloat16(f);  // RNE
  return *reinterpret_cast<unsigned short*>(&h);
}

__device__ inline ushort4 pack4(float4 f) {
  return make_ushort4(f2bf(f.x), f2bf(f.y), f2bf(f.z), f2bf(f.w));
}

// ---------------------------------------------------------------------------
// Kernel 1: per-batch sink index (argmin over valid positions, first-tie).
// ---------------------------------------------------------------------------
__global__ void sink_kernel(const float* __restrict__ pos,
                            const int* __restrict__ mask,
                            int* __restrict__ sink_idx,
                            float* __restrict__ out_tail, int tail_elems) {
  const int b = blockIdx.x;
  __shared__ float sval[256];
  __shared__ int   sidx[256];
  float best = INFINITY;
  int   bidx = 0x7fffffff;
  for (int i = threadIdx.x; i < S; i += 256) {
    float v = (mask[b * S + i] == 0) ? INFINITY : pos[b * S + i];
    if (v < best || (v == best && i < bidx)) { best = v; bidx = i; }
  }
  sval[threadIdx.x] = best;
  sidx[threadIdx.x] = bidx;
  __syncthreads();
  for (int off = 128; off > 0; off >>= 1) {
    if ((int)threadIdx.x < off) {
      float v  = sval[threadIdx.x + off];
      int   ix = sidx[threadIdx.x + off];
      if (v < sval[threadIdx.x] ||
          (v == sval[threadIdx.x] && ix < sidx[threadIdx.x])) {
        sval[threadIdx.x] = v;
        sidx[threadIdx.x] = ix;
      }
    }
    __syncthreads();
  }
  if (threadIdx.x == 0) {
    sink_idx[b] = sidx[0];
    if (b < tail_elems) out_tail[b] = (float)sidx[0];
  }
}

// ---------------------------------------------------------------------------
// Kernel 2: bf16-MFMA GEMM  Y = X @ W^T + b  (fp32 in/out, bf16 compute).
// 128x64 tile, BK=64, 256 threads (4 waves, each a 64x32 output sub-tile).
// Reg-staged global->LDS with inline fp32->bf16 conversion; next K-tile's
// global loads issued right after the barrier (latency hides under MFMA).
// LDS rows are 128 B, XOR-swizzled (byte ^= (row&7)<<4): frag reads 2-way.
// ---------------------------------------------------------------------------
constexpr int GBM = 128, GBN = 64, GBK = 64;

__global__ __launch_bounds__(256) void gemm_mfma_bias(
    const float* __restrict__ X,    // [M,K]
    const float* __restrict__ W,    // [N,K]
    const float* __restrict__ bias, // [N]
    float* __restrict__ Y,          // [M,N]
    int M, int N, int K) {
  __shared__ __align__(16) unsigned char lds[(GBM + GBN) * GBK * 2];
  unsigned char* Xs = lds;                  // [128][64] bf16, swizzled
  unsigned char* Ws = lds + GBM * GBK * 2;  // [64][64]  bf16, swizzled

  const int tid  = threadIdx.x;
  const int lane = tid & 63, w = tid >> 6;
  const int wr = w >> 1, wc = w & 1;
  const int lr = lane & 15, g = lane >> 4;
  const int m0 = blockIdx.y * GBM, n0 = blockIdx.x * GBN;

  float4 xreg[8], wreg[4];

#define LOAD_X(k0)                                                       \
  {                                                                      \
    _Pragma("unroll") for (int i = 0; i < 8; ++i) {                      \
      int f = tid + i * 256, r = f >> 4, c4 = f & 15;                    \
      xreg[i] = *reinterpret_cast<const float4*>(                        \
          &X[(size_t)(m0 + r) * K + (k0) + c4 * 4]);                     \
    }                                                                    \
  }
#define LOAD_W(k0)                                                       \
  {                                                                      \
    _Pragma("unroll") for (int i = 0; i < 4; ++i) {                      \
      int f = tid + i * 256, r = f >> 4, c4 = f & 15;                    \
      wreg[i] = *reinterpret_cast<const float4*>(                        \
          &W[(size_t)(n0 + r) * K + (k0) + c4 * 4]);                     \
    }                                                                    \
  }

  LOAD_X(0);
  LOAD_W(0);

  v4f acc[4][2] = {};
  const int ksteps = K / GBK;

  for (int s = 0; s < ksteps; ++s) {
    // ---- LDS write of the staged (already loaded) tile
#pragma unroll
    for (int i = 0; i < 8; ++i) {
      int f = tid + i * 256, r = f >> 4, c4 = f & 15;
      *reinterpret_cast<ushort4*>(
          Xs + r * 128 + ((c4 * 8) ^ ((r & 7) << 4))) = pack4(xreg[i]);
    }
#pragma unroll
    for (int i = 0; i < 4; ++i) {
      int f = tid + i * 256, r = f >> 4, c4 = f & 15;
      *reinterpret_cast<ushort4*>(
          Ws + r * 128 + ((c4 * 8) ^ ((r & 7) << 4))) = pack4(wreg[i]);
    }
    __syncthreads();
    // ---- prefetch next K-tile (vmem latency hides under MFMA below)
    if (s + 1 < ksteps) {
      LOAD_X((s + 1) * GBK);
      LOAD_W((s + 1) * GBK);
    }
    // ---- fragments + MFMA
    const int sw = (lr & 7) << 4;
#pragma unroll
    for (int ks = 0; ks < 2; ++ks) {
      v8s a[4], bfr[2];
#pragma unroll
      for (int mf = 0; mf < 4; ++mf)
        a[mf] = *reinterpret_cast<const v8s*>(
            Xs + (wr * 64 + mf * 16 + lr) * 128 + ((ks * 64 + g * 16) ^ sw));
#pragma unroll
      for (int nf = 0; nf < 2; ++nf)
        bfr[nf] = *reinterpret_cast<const v8s*>(
            Ws + (wc * 32 + nf * 16 + lr) * 128 + ((ks * 64 + g * 16) ^ sw));
#pragma unroll
      for (int mf = 0; mf < 4; ++mf)
#pragma unroll
        for (int nf = 0; nf < 2; ++nf)
          acc[mf][nf] = mfma_16x16x32_bf16(a[mf], bfr[nf], acc[mf][nf]);
    }
    __syncthreads();
  }
#undef LOAD_X
#undef LOAD_W

  // ---- epilogue: C/D layout col = lane&15 (n), row = g*4 + reg (m)
#pragma unroll
  for (int nf = 0; nf < 2; ++nf) {
    const int n = n0 + wc * 32 + nf * 16 + lr;
    const float bs = bias[n];
#pragma unroll
    for (int mf = 0; mf < 4; ++mf)
#pragma unroll
      for (int r = 0; r < 4; ++r)
        Y[(size_t)(m0 + wr * 64 + mf * 16 + g * 4 + r) * N + n] =
            acc[mf][nf][r] + bs;
  }
}

// ---------------------------------------------------------------------------
// Kernel 3: flash attention, bf16 MFMA, swapped-operand layout (validated
// round 3; unchanged this round).
// ---------------------------------------------------------------------------
constexpr int BQ = 64, BKV = 64;

__device__ inline unsigned swz(int row, int bytecol) {
  return (unsigned)(row * 128 + (bytecol ^ ((row & 7) << 4)));
}

__global__ __launch_bounds__(256) void attn_kernel(
    const float* __restrict__ qg, const float* __restrict__ kg,
    const float* __restrict__ vg, const int* __restrict__ mask,
    const int* __restrict__ sink_idx, float* __restrict__ og) {
  __shared__ __align__(16) unsigned char smem[3 * 64 * 128 + 256];
  unsigned char* Qs  = smem;                 // [64 q][64 d] bf16, swizzled
  unsigned char* Ks  = smem + 8192;          // [64 kv][64 d] bf16, swizzled
  unsigned char* VsT = smem + 16384;         // [64 d][64 kv] bf16, swizzled
  float* sbias = reinterpret_cast<float*>(smem + 24576);  // [64 kv]

  const int b = blockIdx.z, h = blockIdx.y, q0 = blockIdx.x * BQ;
  const int tid  = threadIdx.x;
  const int lane = tid & 63, wv = tid >> 6;
  const int lr = lane & 15, g = lane >> 4;
  const int sb = sink_idx[b];

  // ---- stage Q tile (once): thread t -> row q=t>>2, 16 cols at (t&3)*16
  {
    const int qr = tid >> 2, cb = tid & 3;
    const float* src = qg + ((size_t)b * S + q0 + qr) * D + h * HD + cb * 16;
#pragma unroll
    for (int u = 0; u < 4; ++u) {
      float4 f = *reinterpret_cast<const float4*>(src + u * 4);
      *reinterpret_cast<ushort4*>(Qs + swz(qr, cb * 32 + u * 8)) = pack4(f);
    }
  }

  float m_i = -INFINITY, l_i = 0.f;
  v4f acc[4] = {};  // O^T frags: acc[c] covers d = c*16 + g*4 + r, q = lr

  for (int kv0 = 0; kv0 < S; kv0 += BKV) {
    __syncthreads();  // previous tile's LDS reads done (also fences Q stage)

    // ---- stage K tile
    {
      const int kr = tid >> 2, cb = tid & 3;
      const float* src =
          kg + ((size_t)b * S + kv0 + kr) * D + h * HD + cb * 16;
#pragma unroll
      for (int u = 0; u < 4; ++u) {
        float4 f = *reinterpret_cast<const float4*>(src + u * 4);
        *reinterpret_cast<ushort4*>(Ks + swz(kr, cb * 32 + u * 8)) = pack4(f);
      }
    }
    // ---- stage V^T tile (4x4 in-register transpose per thread)
    {
      const int kvl = (tid >> 4) * 4, d0 = (tid & 15) * 4;
      float4 fr[4];
#pragma unroll
      for (int i = 0; i < 4; ++i)
        fr[i] = *reinterpret_cast<const float4*>(
            vg + ((size_t)b * S + kv0 + kvl + i) * D + h * HD + d0);
      const float* fc = reinterpret_cast<const float*>(fr);
#pragma unroll
      for (int c = 0; c < 4; ++c) {
        ushort4 h4 = make_ushort4(f2bf(fc[0 * 4 + c]), f2bf(fc[1 * 4 + c]),
                                  f2bf(fc[2 * 4 + c]), f2bf(fc[3 * 4 + c]));
        *reinterpret_cast<ushort4*>(VsT + swz(d0 + c, kvl * 2)) = h4;
      }
    }
    // ---- merged mask/sink bias per kv column
    if (tid < BKV) {
      const int kv = kv0 + tid;
      sbias[tid] =
          mask[b * S + kv] ? ((kv == sb) ? SINK_STRENGTH : 0.f) : -1e9f;
    }
    __syncthreads();

    // ---- QK^T (swapped): st[t] = S^T rows [t*16, t*16+16), cols = q
    v4f st[4] = {};
#pragma unroll
    for (int t = 0; t < 4; ++t) {
#pragma unroll
      for (int ks = 0; ks < 2; ++ks) {
        v8s aK = *reinterpret_cast<const v8s*>(
            Ks + swz(t * 16 + lr, ks * 64 + g * 16));
        v8s bQ = *reinterpret_cast<const v8s*>(
            Qs + swz(wv * 16 + lr, ks * 64 + g * 16));
        st[t] = mfma_16x16x32_bf16(aK, bQ, st[t]);
      }
    }

    // ---- scale + bias, online softmax (lane-scalar: this lane's q = lr)
    float s[4][4];
    float mx = -INFINITY;
#pragma unroll
    for (int t = 0; t < 4; ++t) {
      float4 b4 = *reinterpret_cast<const float4*>(&sbias[t * 16 + g * 4]);
      const float bb[4] = {b4.x, b4.y, b4.z, b4.w};
#pragma unroll
      for (int r = 0; r < 4; ++r) {
        s[t][r] = fmaf(st[t][r], SCALE, bb[r]);
        mx = fmaxf(mx, s[t][r]);
      }
    }
    mx = fmaxf(mx, __shfl_xor(mx, 16, 64));
    mx = fmaxf(mx, __shfl_xor(mx, 32, 64));

    const float mn   = fmaxf(m_i, mx);
    const float corr = __expf(m_i - mn);  // exp(-inf)=0 on first tile
    float rs = 0.f;
    v4s pb[4];
#pragma unroll
    for (int t = 0; t < 4; ++t) {
#pragma unroll
      for (int r = 0; r < 4; ++r) {
        float pv = __expf(s[t][r] - mn);
        rs += pv;
        pb[t][r] = (short)f2bf(pv);
      }
    }
    rs += __shfl_xor(rs, 16, 64);
    rs += __shfl_xor(rs, 32, 64);
    l_i = l_i * corr + rs;
    m_i = mn;
#pragma unroll
    for (int c = 0; c < 4; ++c) acc[c] = acc[c] * corr;

    // ---- PV: O^T += V^T-chunk(16d x 16kv) @ P^T-chunk(16kv x 16q)
#pragma unroll
    for (int t = 0; t < 4; ++t) {
#pragma unroll
      for (int c = 0; c < 4; ++c) {
        v4s aV = *reinterpret_cast<const v4s*>(
            VsT + swz(c * 16 + lr, t * 32 + g * 8));
        acc[c] = mfma_16x16x16_bf16(aV, pb[t], acc[c]);
      }
    }
  }

  // ---- epilogue: O[q][d] = O^T/l ; acc[c] reg r -> d = c*16 + g*4 + r
  const float inv = 1.0f / l_i;
  float* orow = og + ((size_t)b * S + q0 + wv * 16 + lr) * D + h * HD;
#pragma unroll
  for (int c = 0; c < 4; ++c) {
    v4f r = acc[c] * inv;
    *reinterpret_cast<v4f*>(orow + c * 16 + g * 4) = r;
  }
}

// ---------------------------------------------------------------------------
// Launch: sink -> Q/K/V projections (bf16 MFMA) -> attention -> O projection.
// Workspace: q | k | v | attn_out (fp32) | sink_idx(int[B])
// ---------------------------------------------------------------------------
extern "C" void kernel_launch(void* const* d_in, const int* in_sizes, int n_in,
                              void* d_out, int out_size, void* d_ws,
                              size_t ws_size, hipStream_t stream) {
  const float* query = (const float*)d_in[0];
  const float* key_  = (const float*)d_in[1];
  const float* value = (const float*)d_in[2];
  const float* pos   = (const float*)d_in[3];
  const int*   amask = (const int*)d_in[4];
  const float* Wq = (const float*)d_in[5];
  const float* bq = (const float*)d_in[6];
  const float* Wk = (const float*)d_in[7];
  const float* bk = (const float*)d_in[8];
  const float* Wv = (const float*)d_in[9];
  const float* bv = (const float*)d_in[10];
  const float* Wo = (const float*)d_in[11];
  const float* bo = (const float*)d_in[12];
  float* out = (float*)d_out;

  float* qp = (float*)d_ws;
  float* kp = qp + (size_t)B * S * D;
  float* vp = kp + (size_t)B * S * D;
  float* ap = vp + (size_t)B * S * D;
  int* sidx = (int*)(ap + (size_t)B * S * D);

  const int tail_elems = out_size - B * S * D;
  sink_kernel<<<B, 256, 0, stream>>>(pos, amask, sidx,
                                     out + (size_t)B * S * D, tail_elems);

  dim3 blk(256);
  dim3 gmm(D / GBN, (B * S) / GBM);  // (16, 32) = 512 blocks
  gemm_mfma_bias<<<gmm, blk, 0, stream>>>(query, Wq, bq, qp, B * S, D, D);
  gemm_mfma_bias<<<gmm, blk, 0, stream>>>(key_, Wk, bk, kp, B * S, D, D);
  gemm_mfma_bias<<<gmm, blk, 0, stream>>>(value, Wv, bv, vp, B * S, D, D);

  attn_kernel<<<dim3(S / BQ, H, B), blk, 0, stream>>>(qp, kp, vp, amask,
                                                      sidx, ap);

  gemm_mfma_bias<<<gmm, blk, 0, stream>>>(ap, Wo, bo, out, B * S, D, D);
}

// Round 6
// 264.051 us; speedup vs baseline: 7.8732x; 1.3281x over previous
//
#include <hip/hip_runtime.h>
#include <hip/hip_bf16.h>
#include <math.h>

// Problem constants (fixed instance: B=2, S=2048, D=1024, H=16)
constexpr int B  = 2;
constexpr int S  = 2048;
constexpr int D  = 1024;
constexpr int H  = 16;
constexpr int HD = 64;                    // head dim = D/H
constexpr float SCALE = 0.125f;           // 1/sqrt(HD)
constexpr float SINK_STRENGTH = 0.1f;

typedef short v4s __attribute__((ext_vector_type(4)));
typedef short v8s __attribute__((ext_vector_type(8)));
typedef float v4f __attribute__((ext_vector_type(4)));

// ---------------------------------------------------------------------------
// MFMA wrappers (layouts HW-validated rounds 3/5)
// ---------------------------------------------------------------------------
__device__ inline v4f mfma_16x16x32_bf16(v8s a, v8s b, v4f c) {
  return __builtin_amdgcn_mfma_f32_16x16x32_bf16(a, b, c, 0, 0, 0);
}

__device__ inline v4f mfma_16x16x16_bf16(v4s a, v4s b, v4f c) {
#if defined(__has_builtin)
#if __has_builtin(__builtin_amdgcn_mfma_f32_16x16x16bf16_1k)
  return __builtin_amdgcn_mfma_f32_16x16x16bf16_1k(a, b, c, 0, 0, 0);
#define MFMA16_DONE 1
#endif
#endif
#ifndef MFMA16_DONE
  v4f d;
  asm volatile("v_mfma_f32_16x16x16_bf16 %0, %1, %2, %3"
               : "=v"(d) : "v"(a), "v"(b), "v"(c));
  return d;
#endif
}

__device__ inline unsigned short f2bf(float f) {
  __hip_bfloat16 h = __float2bfloat16(f);  // RNE
  return *reinterpret_cast<unsigned short*>(&h);
}

__device__ inline ushort4 pack4(float4 f) {
  return make_ushort4(f2bf(f.x), f2bf(f.y), f2bf(f.z), f2bf(f.w));
}

// ---------------------------------------------------------------------------
// global_load_lds (16B/lane): LDS dest = wave-uniform base + lane*16 (linear).
// Read side uses swz(); so the SOURCE col is pre-swizzled with the same XOR
// (involution) -> LDS linear pos (r,c) holds global (r, c ^ ((r&7)<<4)).
// ---------------------------------------------------------------------------
__device__ inline void gld16(const void* g, void* l) {
  __builtin_amdgcn_global_load_lds(
      (const __attribute__((address_space(1))) void*)g,
      (__attribute__((address_space(3))) void*)l, 16, 0, 0);
}

// Stage 8 rows x 128B (1KB) of a row-major bf16 tile (rows of 64 elements).
// gbase: byte addr of tile row 0 col 0; gstride: bytes between rows.
__device__ inline void stage8(const unsigned char* gbase, size_t gstride,
                              unsigned char* ldsbase, int rb, int lane) {
  const int r = rb + (lane >> 3);
  const int c = (lane & 7) * 16;
  const unsigned char* g = gbase + (size_t)r * gstride + (c ^ ((r & 7) << 4));
  gld16(g, ldsbase + rb * 128);
}

__device__ inline unsigned swz(int row, int bytecol) {
  return (unsigned)(row * 128 + (bytecol ^ ((row & 7) << 4)));
}

// ---------------------------------------------------------------------------
// Kernel 0: batched fp32 -> bf16 conversion (inputs + weights, 7 tensors).
// ---------------------------------------------------------------------------
struct CvtArgs {
  const float* src[7];
  unsigned short* dst[7];
  int n[7];
};

__global__ __launch_bounds__(256) void convert_kernel(CvtArgs a) {
  const int t = blockIdx.y;
  const float* s = a.src[t];
  unsigned short* d = a.dst[t];
  const int n = a.n[t];
  for (int i = (blockIdx.x * 256 + threadIdx.x) * 8; i < n;
       i += gridDim.x * 256 * 8) {
    float4 f0 = *reinterpret_cast<const float4*>(s + i);
    float4 f1 = *reinterpret_cast<const float4*>(s + i + 4);
    *reinterpret_cast<ushort4*>(d + i)     = pack4(f0);
    *reinterpret_cast<ushort4*>(d + i + 4) = pack4(f1);
  }
}

// ---------------------------------------------------------------------------
// Kernel 1: per-batch sink index (argmin over valid positions, first-tie)
// + precompute merged per-key bias sbias[b][kv] = mask? (kv==sb?0.1:0) : -1e9.
// ---------------------------------------------------------------------------
__global__ void sink_kernel(const float* __restrict__ pos,
                            const int* __restrict__ mask,
                            int* __restrict__ sink_idx,
                            float* __restrict__ sbias_g,
                            float* __restrict__ out_tail, int tail_elems) {
  const int b = blockIdx.x;
  __shared__ float sval[256];
  __shared__ int   sidx[256];
  float best = INFINITY;
  int   bidx = 0x7fffffff;
  for (int i = threadIdx.x; i < S; i += 256) {
    float v = (mask[b * S + i] == 0) ? INFINITY : pos[b * S + i];
    if (v < best || (v == best && i < bidx)) { best = v; bidx = i; }
  }
  sval[threadIdx.x] = best;
  sidx[threadIdx.x] = bidx;
  __syncthreads();
  for (int off = 128; off > 0; off >>= 1) {
    if ((int)threadIdx.x < off) {
      float v  = sval[threadIdx.x + off];
      int   ix = sidx[threadIdx.x + off];
      if (v < sval[threadIdx.x] ||
          (v == sval[threadIdx.x] && ix < sidx[threadIdx.x])) {
        sval[threadIdx.x] = v;
        sidx[threadIdx.x] = ix;
      }
    }
    __syncthreads();
  }
  const int sb = sidx[0];
  if (threadIdx.x == 0) {
    sink_idx[b] = sb;
    if (b < tail_elems) out_tail[b] = (float)sb;
  }
  for (int i = threadIdx.x; i < S; i += 256)
    sbias_g[b * S + i] =
        mask[b * S + i] ? ((i == sb) ? SINK_STRENGTH : 0.f) : -1e9f;
}

// ---------------------------------------------------------------------------
// Kernel 2: bf16-in GEMM  Y = X @ W^T + b.  128x64 tile, BK=64, 4 waves.
// Double-buffered LDS; global_load_lds staging issued right after the (single)
// per-K-step barrier so loads overlap the MFMA phase.
// MODE 0: bf16 row-major out. MODE 1: bf16 V^T out [B][H][HD][S]. MODE 2: f32.
// ---------------------------------------------------------------------------
template <int MODE>
__global__ __launch_bounds__(256) void gemm_bf16(
    const unsigned short* __restrict__ X,   // [M,K] bf16
    const unsigned short* __restrict__ Wb,  // [N,K] bf16
    const float* __restrict__ bias,         // [N] fp32
    void* __restrict__ Yv, int M, int N, int K) {
  __shared__ __align__(16) unsigned char lds[2 * 24576];  // (X 16K + W 8K) x2
  const int tid = threadIdx.x, lane = tid & 63, w = tid >> 6;
  const int wr = w >> 1, wc = w & 1, lr = lane & 15, g = lane >> 4;
  const int m0 = blockIdx.y * 128, n0 = blockIdx.x * 64;
  const unsigned char* xg = (const unsigned char*)(X + (size_t)m0 * K);
  const unsigned char* wg = (const unsigned char*)(Wb + (size_t)n0 * K);
  const size_t stride = (size_t)K * 2;

  auto stage = [&](int buf, int k0) {
    unsigned char* Xs = lds + buf * 24576;
    unsigned char* Ws = Xs + 16384;
    const unsigned char* xk = xg + k0 * 2;
    const unsigned char* wk = wg + k0 * 2;
#pragma unroll
    for (int u = 0; u < 4; ++u) stage8(xk, stride, Xs, w * 32 + u * 8, lane);
#pragma unroll
    for (int u = 0; u < 2; ++u) stage8(wk, stride, Ws, w * 16 + u * 8, lane);
  };

  stage(0, 0);
  v4f acc[4][2] = {};
  const int ksteps = K / 64;
  int cur = 0;
  for (int s = 0; s < ksteps; ++s) {
    __syncthreads();  // drains vmcnt: buf[cur] ready; prev reads done
    if (s + 1 < ksteps) stage(cur ^ 1, (s + 1) * 64);  // async, overlaps MFMA
    const unsigned char* Xs = lds + cur * 24576;
    const unsigned char* Ws = Xs + 16384;
    const int sw = (lr & 7) << 4;
#pragma unroll
    for (int ks = 0; ks < 2; ++ks) {
      v8s a[4], bf2[2];
#pragma unroll
      for (int mf = 0; mf < 4; ++mf)
        a[mf] = *reinterpret_cast<const v8s*>(
            Xs + (wr * 64 + mf * 16 + lr) * 128 + ((ks * 64 + g * 16) ^ sw));
#pragma unroll
      for (int nf = 0; nf < 2; ++nf)
        bf2[nf] = *reinterpret_cast<const v8s*>(
            Ws + (wc * 32 + nf * 16 + lr) * 128 + ((ks * 64 + g * 16) ^ sw));
#pragma unroll
      for (int mf = 0; mf < 4; ++mf)
#pragma unroll
        for (int nf = 0; nf < 2; ++nf)
          acc[mf][nf] = mfma_16x16x32_bf16(a[mf], bf2[nf], acc[mf][nf]);
    }
    cur ^= 1;
  }

  // epilogue: C/D layout col = lane&15 (n), row = g*4 + reg (m)
  if constexpr (MODE == 2) {
    float* Y = (float*)Yv;
#pragma unroll
    for (int nf = 0; nf < 2; ++nf) {
      const int n = n0 + wc * 32 + nf * 16 + lr;
      const float bs = bias[n];
#pragma unroll
      for (int mf = 0; mf < 4; ++mf)
#pragma unroll
        for (int r = 0; r < 4; ++r)
          Y[(size_t)(m0 + wr * 64 + mf * 16 + g * 4 + r) * N + n] =
              acc[mf][nf][r] + bs;
    }
  } else if constexpr (MODE == 0) {
    unsigned short* Y = (unsigned short*)Yv;
#pragma unroll
    for (int nf = 0; nf < 2; ++nf) {
      const int n = n0 + wc * 32 + nf * 16 + lr;
      const float bs = bias[n];
#pragma unroll
      for (int mf = 0; mf < 4; ++mf)
#pragma unroll
        for (int r = 0; r < 4; ++r)
          Y[(size_t)(m0 + wr * 64 + mf * 16 + g * 4 + r) * N + n] =
              f2bf(acc[mf][nf][r] + bs);
    }
  } else {  // MODE 1: V^T bf16, [B][H][HD][S]
    unsigned short* Y = (unsigned short*)Yv;
#pragma unroll
    for (int nf = 0; nf < 2; ++nf) {
      const int n = n0 + wc * 32 + nf * 16 + lr;
      const int hh = n >> 6, dd = n & 63;
      const float bs = bias[n];
#pragma unroll
      for (int mf = 0; mf < 4; ++mf) {
        const int m = m0 + wr * 64 + mf * 16 + g * 4;
        const int bb = m >> 11, ss = m & 2047;
        float4 f = make_float4(acc[mf][nf][0] + bs, acc[mf][nf][1] + bs,
                               acc[mf][nf][2] + bs, acc[mf][nf][3] + bs);
        *reinterpret_cast<ushort4*>(
            &Y[(((size_t)bb * H + hh) * HD + dd) * S + ss]) = pack4(f);
      }
    }
  }
}

// ---------------------------------------------------------------------------
// Kernel 3: flash attention, bf16 MFMA, swapped-operand layout.
// All inputs pre-converted bf16 (K row-major, V pre-transposed [B][H][HD][S]);
// staging = pure global_load_lds, K/V double-buffered, ONE barrier per tile
// (stage of tile t+1 overlaps QK/softmax/PV of tile t). Output bf16.
// ---------------------------------------------------------------------------
__global__ __launch_bounds__(256) void attn_kernel(
    const unsigned short* __restrict__ qg, const unsigned short* __restrict__ kg,
    const unsigned short* __restrict__ vt, const float* __restrict__ sbias_g,
    unsigned short* __restrict__ og) {
  __shared__ __align__(16) unsigned char smem[8192 + 2 * 16384];  // Q | (K,V)x2
  const int b = blockIdx.z, h = blockIdx.y, q0 = blockIdx.x * 64;
  const int tid = threadIdx.x, lane = tid & 63, wv = tid >> 6;
  const int lr = lane & 15, g = lane >> 4;

  const unsigned char* qgb =
      (const unsigned char*)(qg + ((size_t)b * S + q0) * D + h * HD);
  const unsigned char* kgb0 =
      (const unsigned char*)(kg + (size_t)b * S * D + h * HD);
  const unsigned char* vtb =
      (const unsigned char*)(vt + ((size_t)b * H + h) * HD * S);

  // stage Q (once) and K/V tile 0
  stage8(qgb, D * 2, smem, wv * 16, lane);
  stage8(qgb, D * 2, smem, wv * 16 + 8, lane);
  {
    unsigned char* Ks = smem + 8192;
    unsigned char* Vs = Ks + 8192;
    stage8(kgb0, D * 2, Ks, wv * 16, lane);
    stage8(kgb0, D * 2, Ks, wv * 16 + 8, lane);
    stage8(vtb, S * 2, Vs, wv * 16, lane);
    stage8(vtb, S * 2, Vs, wv * 16 + 8, lane);
  }

  float m_i = -INFINITY, l_i = 0.f;
  v4f acc[4] = {};  // O^T frags: acc[c] covers d = c*16 + g*4 + r, q = lr
  v8s qf[2];
  int cur = 0;

  for (int kv0 = 0; kv0 < S; kv0 += 64) {
    __syncthreads();  // vmcnt drain: buf[cur] (and Q) ready; prev reads done
    const unsigned char* Ks = smem + 8192 + cur * 16384;
    const unsigned char* Vs = Ks + 8192;

    // sbias loads FIRST (older than stage glds -> waiting on them doesn't
    // drain the prefetch queue)
    float4 b4[4];
#pragma unroll
    for (int t = 0; t < 4; ++t)
      b4[t] = *reinterpret_cast<const float4*>(
          &sbias_g[b * S + kv0 + t * 16 + g * 4]);

    // prefetch next K/V tile (async, overlaps compute below)
    if (kv0 + 64 < S) {
      unsigned char* Kn = smem + 8192 + (cur ^ 1) * 16384;
      unsigned char* Vn = Kn + 8192;
      const unsigned char* kgb = kgb0 + (size_t)(kv0 + 64) * (D * 2);
      const unsigned char* vgb = vtb + (size_t)(kv0 + 64) * 2;
      stage8(kgb, D * 2, Kn, wv * 16, lane);
      stage8(kgb, D * 2, Kn, wv * 16 + 8, lane);
      stage8(vgb, S * 2, Vn, wv * 16, lane);
      stage8(vgb, S * 2, Vn, wv * 16 + 8, lane);
    }

    if (kv0 == 0) {  // hoist Q fragments (uniform branch, once)
      qf[0] = *reinterpret_cast<const v8s*>(smem + swz(wv * 16 + lr, g * 16));
      qf[1] = *reinterpret_cast<const v8s*>(
          smem + swz(wv * 16 + lr, 64 + g * 16));
    }

    // ---- QK^T (swapped): st[t] = S^T rows [t*16,+16), cols = q
    v4f st[4] = {};
#pragma unroll
    for (int t = 0; t < 4; ++t) {
#pragma unroll
      for (int ks = 0; ks < 2; ++ks) {
        v8s aK = *reinterpret_cast<const v8s*>(
            Ks + swz(t * 16 + lr, ks * 64 + g * 16));
        st[t] = mfma_16x16x32_bf16(aK, qf[ks], st[t]);
      }
    }

    // ---- scale + bias, online softmax (lane-scalar: this lane's q = lr)
    float s[4][4];
    float mx = -INFINITY;
#pragma unroll
    for (int t = 0; t < 4; ++t) {
      const float bb[4] = {b4[t].x, b4[t].y, b4[t].z, b4[t].w};
#pragma unroll
      for (int r = 0; r < 4; ++r) {
        s[t][r] = fmaf(st[t][r], SCALE, bb[r]);
        mx = fmaxf(mx, s[t][r]);
      }
    }
    mx = fmaxf(mx, __shfl_xor(mx, 16, 64));
    mx = fmaxf(mx, __shfl_xor(mx, 32, 64));

    const float mn   = fmaxf(m_i, mx);
    const float corr = __expf(m_i - mn);  // exp(-inf)=0 on first tile
    float rs = 0.f;
    v4s pb[4];
#pragma unroll
    for (int t = 0; t < 4; ++t) {
#pragma unroll
      for (int r = 0; r < 4; ++r) {
        float pv = __expf(s[t][r] - mn);
        rs += pv;
        pb[t][r] = (short)f2bf(pv);
      }
    }
    rs += __shfl_xor(rs, 16, 64);
    rs += __shfl_xor(rs, 32, 64);
    l_i = l_i * corr + rs;
    m_i = mn;
#pragma unroll
    for (int c = 0; c < 4; ++c) acc[c] = acc[c] * corr;

    // ---- PV: O^T += V^T-chunk(16d x 16kv) @ P^T-chunk(16kv x 16q)
#pragma unroll
    for (int t = 0; t < 4; ++t) {
#pragma unroll
      for (int c = 0; c < 4; ++c) {
        v4s aV = *reinterpret_cast<const v4s*>(
            Vs + swz(c * 16 + lr, t * 32 + g * 8));
        acc[c] = mfma_16x16x16_bf16(aV, pb[t], acc[c]);
      }
    }
    cur ^= 1;
  }

  // ---- epilogue: O[q][d] = O^T/l, bf16 out
  const float inv = 1.0f / l_i;
  unsigned short* orow = og + ((size_t)b * S + q0 + wv * 16 + lr) * D + h * HD;
#pragma unroll
  for (int c = 0; c < 4; ++c) {
    float4 f = make_float4(acc[c][0] * inv, acc[c][1] * inv, acc[c][2] * inv,
                           acc[c][3] * inv);
    *reinterpret_cast<ushort4*>(orow + c * 16 + g * 4) = pack4(f);
  }
}

// ---------------------------------------------------------------------------
// Launch. ws layout (bf16 elements unless noted):
//   qx|kx|vx [B*S*D each]  (input conversions; qx reused as attn-out ab)
//   wqb|wkb|wvb|wob [D*D each]
//   qb|kb [B*S*D]   vt [B*S*D]   sbias f32[B*S]   sidx int[B]
// total ~58.7 MB (< previous 67.1 MB usage).
// ---------------------------------------------------------------------------
extern "C" void kernel_launch(void* const* d_in, const int* in_sizes, int n_in,
                              void* d_out, int out_size, void* d_ws,
                              size_t ws_size, hipStream_t stream) {
  const float* query = (const float*)d_in[0];
  const float* key_  = (const float*)d_in[1];
  const float* value = (const float*)d_in[2];
  const float* pos   = (const float*)d_in[3];
  const int*   amask = (const int*)d_in[4];
  const float* Wq = (const float*)d_in[5];
  const float* bq = (const float*)d_in[6];
  const float* Wk = (const float*)d_in[7];
  const float* bk = (const float*)d_in[8];
  const float* Wv = (const float*)d_in[9];
  const float* bv = (const float*)d_in[10];
  const float* Wo = (const float*)d_in[11];
  const float* bo = (const float*)d_in[12];
  float* out = (float*)d_out;

  constexpr size_t NBSD = (size_t)B * S * D;  // 4,194,304
  constexpr size_t NDD  = (size_t)D * D;      // 1,048,576
  unsigned short* qx  = (unsigned short*)d_ws;
  unsigned short* kx  = qx + NBSD;
  unsigned short* vx  = kx + NBSD;
  unsigned short* wqb = vx + NBSD;
  unsigned short* wkb = wqb + NDD;
  unsigned short* wvb = wkb + NDD;
  unsigned short* wob = wvb + NDD;
  unsigned short* qb  = wob + NDD;
  unsigned short* kb  = qb + NBSD;
  unsigned short* vt  = kb + NBSD;
  float* sbias_g = (float*)(vt + NBSD);
  int*   sidx    = (int*)(sbias_g + B * S);
  unsigned short* ab = qx;  // reuse: qx dead after Q-projection

  CvtArgs ca;
  ca.src[0] = query; ca.dst[0] = qx;  ca.n[0] = (int)NBSD;
  ca.src[1] = key_;  ca.dst[1] = kx;  ca.n[1] = (int)NBSD;
  ca.src[2] = value; ca.dst[2] = vx;  ca.n[2] = (int)NBSD;
  ca.src[3] = Wq;    ca.dst[3] = wqb; ca.n[3] = (int)NDD;
  ca.src[4] = Wk;    ca.dst[4] = wkb; ca.n[4] = (int)NDD;
  ca.src[5] = Wv;    ca.dst[5] = wvb; ca.n[5] = (int)NDD;
  ca.src[6] = Wo;    ca.dst[6] = wob; ca.n[6] = (int)NDD;
  convert_kernel<<<dim3(2048, 7), 256, 0, stream>>>(ca);

  const int tail_elems = out_size - (int)NBSD;
  sink_kernel<<<B, 256, 0, stream>>>(pos, amask, sidx, sbias_g,
                                     out + NBSD, tail_elems);

  dim3 blk(256);
  dim3 gmm(D / 64, (B * S) / 128);  // (16, 32) = 512 blocks
  gemm_bf16<0><<<gmm, blk, 0, stream>>>(qx, wqb, bq, qb, B * S, D, D);
  gemm_bf16<0><<<gmm, blk, 0, stream>>>(kx, wkb, bk, kb, B * S, D, D);
  gemm_bf16<1><<<gmm, blk, 0, stream>>>(vx, wvb, bv, vt, B * S, D, D);

  attn_kernel<<<dim3(S / 64, H, B), blk, 0, stream>>>(qb, kb, vt, sbias_g, ab);

  gemm_bf16<2><<<gmm, blk, 0, stream>>>(ab, wob, bo, out, B * S, D, D);
}

// Round 11
// 260.421 us; speedup vs baseline: 7.9830x; 1.0139x over previous
//
#include <hip/hip_runtime.h>
#include <hip/hip_bf16.h>
#include <math.h>

// Problem constants (fixed instance: B=2, S=2048, D=1024, H=16)
constexpr int B  = 2;
constexpr int S  = 2048;
constexpr int D  = 1024;
constexpr int H  = 16;
constexpr int HD = 64;
constexpr float SINK_STRENGTH = 0.1f;
constexpr float LOG2E  = 1.4426950408889634f;
constexpr float SCALE2 = 0.125f * LOG2E;       // score scale in log2 domain
constexpr float THR2   = 8.0f * LOG2E;         // defer-max threshold (T13)

typedef short v4s __attribute__((ext_vector_type(4)));
typedef short v8s __attribute__((ext_vector_type(8)));
typedef float v4f __attribute__((ext_vector_type(4)));

// exp2 via the raw v_exp_f32 instruction (D = 2^S0). NOTE: __exp2f is NOT a
// HIP device function on this toolchain (glibc macro collision) — round-10
// compile failure. __builtin_amdgcn_exp2f is the portable spelling.
__device__ inline float exp2_fast(float x) {
  return __builtin_amdgcn_exp2f(x);
}

__device__ inline v4f mfma_16x16x32_bf16(v8s a, v8s b, v4f c) {
  return __builtin_amdgcn_mfma_f32_16x16x32_bf16(a, b, c, 0, 0, 0);
}

__device__ inline v4f mfma_16x16x16_bf16(v4s a, v4s b, v4f c) {
#if defined(__has_builtin)
#if __has_builtin(__builtin_amdgcn_mfma_f32_16x16x16bf16_1k)
  return __builtin_amdgcn_mfma_f32_16x16x16bf16_1k(a, b, c, 0, 0, 0);
#define MFMA16_DONE 1
#endif
#endif
#ifndef MFMA16_DONE
  v4f d;
  asm volatile("v_mfma_f32_16x16x16_bf16 %0, %1, %2, %3"
               : "=v"(d) : "v"(a), "v"(b), "v"(c));
  return d;
#endif
}

__device__ inline unsigned short f2bf(float f) {
  __hip_bfloat16 h = __float2bfloat16(f);  // RNE
  return *reinterpret_cast<unsigned short*>(&h);
}

__device__ inline ushort4 pack4(float4 f) {
  return make_ushort4(f2bf(f.x), f2bf(f.y), f2bf(f.z), f2bf(f.w));
}

// ---------------------------------------------------------------------------
// global_load_lds staging (rule 21: linear LDS dest, inverse-swizzled source,
// swizzled read). stage8 = 8 rows x 128B per wave call.
// ---------------------------------------------------------------------------
__device__ inline void gld16(const void* g, void* l) {
  __builtin_amdgcn_global_load_lds(
      (const __attribute__((address_space(1))) void*)g,
      (__attribute__((address_space(3))) void*)l, 16, 0, 0);
}

__device__ inline void stage8(const unsigned char* gbase, size_t gstride,
                              unsigned char* ldsbase, int rb, int lane) {
  const int r = rb + (lane >> 3);
  const int c = (lane & 7) * 16;
  const unsigned char* g = gbase + (size_t)r * gstride + (c ^ ((r & 7) << 4));
  gld16(g, ldsbase + rb * 128);
}

__device__ inline unsigned swz(int row, int bytecol) {
  return (unsigned)(row * 128 + (bytecol ^ ((row & 7) << 4)));
}

// ---------------------------------------------------------------------------
// Kernel 0: batched fp32 -> bf16 conversion (3 inputs + 4 weights).
// ---------------------------------------------------------------------------
struct CvtArgs {
  const float* src[7];
  unsigned short* dst[7];
  int n[7];
};

__global__ __launch_bounds__(256) void convert_kernel(CvtArgs a) {
  const int t = blockIdx.y;
  const float* s = a.src[t];
  unsigned short* d = a.dst[t];
  const int n = a.n[t];
  for (int i = (blockIdx.x * 256 + threadIdx.x) * 8; i < n;
       i += gridDim.x * 256 * 8) {
    float4 f0 = *reinterpret_cast<const float4*>(s + i);
    float4 f1 = *reinterpret_cast<const float4*>(s + i + 4);
    *reinterpret_cast<ushort4*>(d + i)     = pack4(f0);
    *reinterpret_cast<ushort4*>(d + i + 4) = pack4(f1);
  }
}

// ---------------------------------------------------------------------------
// Kernel 1: sink index (argmin over valid positions, first-tie) + merged
// per-key bias, PRE-SCALED by log2e: sbias2 = (mask? (kv==sb?0.1:0):-1e9)*log2e
// ---------------------------------------------------------------------------
__global__ void sink_kernel(const float* __restrict__ pos,
                            const int* __restrict__ mask,
                            float* __restrict__ sbias_g,
                            float* __restrict__ out_tail, int tail_elems) {
  const int b = blockIdx.x;
  __shared__ float sval[256];
  __shared__ int   sidx[256];
  float best = INFINITY;
  int   bidx = 0x7fffffff;
  for (int i = threadIdx.x; i < S; i += 256) {
    float v = (mask[b * S + i] == 0) ? INFINITY : pos[b * S + i];
    if (v < best || (v == best && i < bidx)) { best = v; bidx = i; }
  }
  sval[threadIdx.x] = best;
  sidx[threadIdx.x] = bidx;
  __syncthreads();
  for (int off = 128; off > 0; off >>= 1) {
    if ((int)threadIdx.x < off) {
      float v  = sval[threadIdx.x + off];
      int   ix = sidx[threadIdx.x + off];
      if (v < sval[threadIdx.x] ||
          (v == sval[threadIdx.x] && ix < sidx[threadIdx.x])) {
        sval[threadIdx.x] = v;
        sidx[threadIdx.x] = ix;
      }
    }
    __syncthreads();
  }
  const int sb = sidx[0];
  if (threadIdx.x == 0 && b < tail_elems) out_tail[b] = (float)sb;
  for (int i = threadIdx.x; i < S; i += 256)
    sbias_g[b * S + i] =
        (mask[b * S + i] ? ((i == sb) ? SINK_STRENGTH : 0.f) : -1e9f) * LOG2E;
}

// ---------------------------------------------------------------------------
// Kernel 2: FUSED Q/K/V projection GEMM. 128x128 tile, BK=64, 4 waves (each
// 64x64 out, 4x4 frags -> 32 MFMA : 16 ds_read : 8 gld16 per wave-K-step =
// m97 density). Grid 768 (1D), XCD-chunked. z=2 (V) writes V^T [B][H][HD][S].
// ---------------------------------------------------------------------------
struct QKVArgs {
  const unsigned short* x[3];
  const unsigned short* w[3];
  const float* bias[3];
  unsigned short* y[3];
};

__global__ __launch_bounds__(256) void gemm_qkv(QKVArgs args) {
  __shared__ __align__(16) unsigned char lds[2 * 32768];  // (X 16K + W 16K) x2
  int id = blockIdx.x;
  id = (id & 7) * 96 + (id >> 3);  // XCD-chunked bijection (768 % 8 == 0)
  const int z = id >> 8, rem = id & 255;
  const int m0 = (rem >> 3) * 128, n0 = (rem & 7) * 128;

  const int tid = threadIdx.x, lane = tid & 63, w = tid >> 6;
  const int wr = w >> 1, wc = w & 1, lr = lane & 15, g = lane >> 4;
  const unsigned short* X  = args.x[z];
  const unsigned short* Wb = args.w[z];
  const unsigned char* xg = (const unsigned char*)(X + (size_t)m0 * D);
  const unsigned char* wg = (const unsigned char*)(Wb + (size_t)n0 * D);
  const size_t stride = (size_t)D * 2;

  auto stage = [&](int buf, int k0) {
    unsigned char* Xs = lds + buf * 32768;
    unsigned char* Ws = Xs + 16384;
    const unsigned char* xk = xg + (size_t)k0 * 2;
    const unsigned char* wk = wg + (size_t)k0 * 2;
#pragma unroll
    for (int u = 0; u < 4; ++u) stage8(xk, stride, Xs, w * 32 + u * 8, lane);
#pragma unroll
    for (int u = 0; u < 4; ++u) stage8(wk, stride, Ws, w * 32 + u * 8, lane);
  };

  stage(0, 0);
  v4f acc[4][4] = {};
  const int ksteps = D / 64;
  int cur = 0;
  for (int s = 0; s < ksteps; ++s) {
    __syncthreads();  // buf[cur] ready (vmcnt drained); prev reads done
    if (s + 1 < ksteps) stage(cur ^ 1, (s + 1) * 64);  // overlaps MFMA below
    const unsigned char* Xs = lds + cur * 32768;
    const unsigned char* Ws = Xs + 16384;
    const int sw = (lr & 7) << 4;
#pragma unroll
    for (int ks = 0; ks < 2; ++ks) {
      v8s a[4], bb[4];
#pragma unroll
      for (int mf = 0; mf < 4; ++mf)
        a[mf] = *reinterpret_cast<const v8s*>(
            Xs + (wr * 64 + mf * 16 + lr) * 128 + ((ks * 64 + g * 16) ^ sw));
#pragma unroll
      for (int nf = 0; nf < 4; ++nf)
        bb[nf] = *reinterpret_cast<const v8s*>(
            Ws + (wc * 64 + nf * 16 + lr) * 128 + ((ks * 64 + g * 16) ^ sw));
#pragma unroll
      for (int mf = 0; mf < 4; ++mf)
#pragma unroll
        for (int nf = 0; nf < 4; ++nf)
          acc[mf][nf] = mfma_16x16x32_bf16(a[mf], bb[nf], acc[mf][nf]);
    }
    cur ^= 1;
  }

  // epilogue: C/D layout col = lane&15 (n), row = g*4 + reg (m)
  const float* bias = args.bias[z];
  unsigned short* Y = args.y[z];
  if (z < 2) {  // Q, K: bf16 row-major [B*S, D]
#pragma unroll
    for (int nf = 0; nf < 4; ++nf) {
      const int n = n0 + wc * 64 + nf * 16 + lr;
      const float bs = bias[n];
#pragma unroll
      for (int mf = 0; mf < 4; ++mf)
#pragma unroll
        for (int r = 0; r < 4; ++r)
          Y[(size_t)(m0 + wr * 64 + mf * 16 + g * 4 + r) * D + n] =
              f2bf(acc[mf][nf][r] + bs);
    }
  } else {  // V: bf16 V^T [B][H][HD][S]
#pragma unroll
    for (int nf = 0; nf < 4; ++nf) {
      const int n = n0 + wc * 64 + nf * 16 + lr;
      const int hh = n >> 6, dd = n & 63;
      const float bs = bias[n];
#pragma unroll
      for (int mf = 0; mf < 4; ++mf) {
        const int m = m0 + wr * 64 + mf * 16 + g * 4;
        const int bb2 = m >> 11, ss = m & 2047;
        float4 f = make_float4(acc[mf][nf][0] + bs, acc[mf][nf][1] + bs,
                               acc[mf][nf][2] + bs, acc[mf][nf][3] + bs);
        *reinterpret_cast<ushort4*>(
            &Y[(((size_t)bb2 * H + hh) * HD + dd) * S + ss]) = pack4(f);
      }
    }
  }
}

// ---------------------------------------------------------------------------
// Kernel 3: O projection, bf16-in fp32-out. 128x64 tile, BK=64.
// ---------------------------------------------------------------------------
__global__ __launch_bounds__(256) void gemm_o(
    const unsigned short* __restrict__ X, const unsigned short* __restrict__ Wb,
    const float* __restrict__ bias, float* __restrict__ Y) {
  __shared__ __align__(16) unsigned char lds[2 * 24576];
  const int tid = threadIdx.x, lane = tid & 63, w = tid >> 6;
  const int wr = w >> 1, wc = w & 1, lr = lane & 15, g = lane >> 4;
  const int m0 = blockIdx.y * 128, n0 = blockIdx.x * 64;
  const unsigned char* xg = (const unsigned char*)(X + (size_t)m0 * D);
  const unsigned char* wg = (const unsigned char*)(Wb + (size_t)n0 * D);
  const size_t stride = (size_t)D * 2;

  auto stage = [&](int buf, int k0) {
    unsigned char* Xs = lds + buf * 24576;
    unsigned char* Ws = Xs + 16384;
    const unsigned char* xk = xg + (size_t)k0 * 2;
    const unsigned char* wk = wg + (size_t)k0 * 2;
#pragma unroll
    for (int u = 0; u < 4; ++u) stage8(xk, stride, Xs, w * 32 + u * 8, lane);
#pragma unroll
    for (int u = 0; u < 2; ++u) stage8(wk, stride, Ws, w * 16 + u * 8, lane);
  };

  stage(0, 0);
  v4f acc[4][2] = {};
  const int ksteps = D / 64;
  int cur = 0;
  for (int s = 0; s < ksteps; ++s) {
    __syncthreads();
    if (s + 1 < ksteps) stage(cur ^ 1, (s + 1) * 64);
    const unsigned char* Xs = lds + cur * 24576;
    const unsigned char* Ws = Xs + 16384;
    const int sw = (lr & 7) << 4;
#pragma unroll
    for (int ks = 0; ks < 2; ++ks) {
      v8s a[4], bf2[2];
#pragma unroll
      for (int mf = 0; mf < 4; ++mf)
        a[mf] = *reinterpret_cast<const v8s*>(
            Xs + (wr * 64 + mf * 16 + lr) * 128 + ((ks * 64 + g * 16) ^ sw));
#pragma unroll
      for (int nf = 0; nf < 2; ++nf)
        bf2[nf] = *reinterpret_cast<const v8s*>(
            Ws + (wc * 32 + nf * 16 + lr) * 128 + ((ks * 64 + g * 16) ^ sw));
#pragma unroll
      for (int mf = 0; mf < 4; ++mf)
#pragma unroll
        for (int nf = 0; nf < 2; ++nf)
          acc[mf][nf] = mfma_16x16x32_bf16(a[mf], bf2[nf], acc[mf][nf]);
    }
    cur ^= 1;
  }
#pragma unroll
  for (int nf = 0; nf < 2; ++nf) {
    const int n = n0 + wc * 32 + nf * 16 + lr;
    const float bs = bias[n];
#pragma unroll
    for (int mf = 0; mf < 4; ++mf)
#pragma unroll
      for (int r = 0; r < 4; ++r)
        Y[(size_t)(m0 + wr * 64 + mf * 16 + g * 4 + r) * D + n] =
            acc[mf][nf][r] + bs;
  }
}

// ---------------------------------------------------------------------------
// Kernel 4: flash attention, bf16 MFMA, swapped-operand layout.
// log2-domain online softmax + defer-max (T13) + setprio (T5) + XCD-chunked
// 1D grid (each XCD = 4 complete (b,h) groups -> K/V working set 2MB < L2).
// ---------------------------------------------------------------------------
__global__ __launch_bounds__(256) void attn_kernel(
    const unsigned short* __restrict__ qg, const unsigned short* __restrict__ kg,
    const unsigned short* __restrict__ vt, const float* __restrict__ sbias_g,
    unsigned short* __restrict__ og) {
  __shared__ __align__(16) unsigned char smem[8192 + 2 * 16384];  // Q | (K,V)x2
  int id = blockIdx.x;
  id = (id & 7) * 128 + (id >> 3);  // XCD-chunked bijection (1024 % 8 == 0)
  const int q0 = (id & 31) * 64, hb = id >> 5;
  const int h = hb & 15, b = hb >> 4;

  const int tid = threadIdx.x, lane = tid & 63, wv = tid >> 6;
  const int lr = lane & 15, g = lane >> 4;

  const unsigned char* qgb =
      (const unsigned char*)(qg + ((size_t)b * S + q0) * D + h * HD);
  const unsigned char* kgb0 =
      (const unsigned char*)(kg + (size_t)b * S * D + h * HD);
  const unsigned char* vtb =
      (const unsigned char*)(vt + ((size_t)b * H + h) * HD * S);

  // prologue: stage Q and K/V tile 0, drain, hoist Q fragments
  stage8(qgb, D * 2, smem, wv * 16, lane);
  stage8(qgb, D * 2, smem, wv * 16 + 8, lane);
  {
    unsigned char* Ks = smem + 8192;
    unsigned char* Vs = Ks + 8192;
    stage8(kgb0, D * 2, Ks, wv * 16, lane);
    stage8(kgb0, D * 2, Ks, wv * 16 + 8, lane);
    stage8(vtb, S * 2, Vs, wv * 16, lane);
    stage8(vtb, S * 2, Vs, wv * 16 + 8, lane);
  }
  __syncthreads();
  v8s qf[2];
  qf[0] = *reinterpret_cast<const v8s*>(smem + swz(wv * 16 + lr, g * 16));
  qf[1] = *reinterpret_cast<const v8s*>(smem + swz(wv * 16 + lr, 64 + g * 16));

  float m_i = -INFINITY, l_i = 0.f;  // m_i in log2 domain
  v4f acc[4] = {};  // O^T frags: acc[c] covers d = c*16 + g*4 + r, q = lr
  int cur = 0;

  for (int kv0 = 0; kv0 < S; kv0 += 64) {
    const unsigned char* Ks = smem + 8192 + cur * 16384;
    const unsigned char* Vs = Ks + 8192;

    // sbias loads FIRST (older than the stage glds below -> waiting on them
    // doesn't drain the prefetch queue)
    float4 b4[4];
#pragma unroll
    for (int t = 0; t < 4; ++t)
      b4[t] = *reinterpret_cast<const float4*>(
          &sbias_g[b * S + kv0 + t * 16 + g * 4]);

    // prefetch next K/V tile (async, overlaps all compute below)
    if (kv0 + 64 < S) {
      unsigned char* Kn = smem + 8192 + (cur ^ 1) * 16384;
      unsigned char* Vn = Kn + 8192;
      const unsigned char* kgb = kgb0 + (size_t)(kv0 + 64) * (D * 2);
      const unsigned char* vgb = vtb + (size_t)(kv0 + 64) * 2;
      stage8(kgb, D * 2, Kn, wv * 16, lane);
      stage8(kgb, D * 2, Kn, wv * 16 + 8, lane);
      stage8(vgb, S * 2, Vn, wv * 16, lane);
      stage8(vgb, S * 2, Vn, wv * 16 + 8, lane);
    }

    // ---- QK^T (swapped): st[t] = S^T rows [t*16,+16), cols = q
    v4f st[4] = {};
    __builtin_amdgcn_s_setprio(1);
#pragma unroll
    for (int t = 0; t < 4; ++t) {
#pragma unroll
      for (int ks = 0; ks < 2; ++ks) {
        v8s aK = *reinterpret_cast<const v8s*>(
            Ks + swz(t * 16 + lr, ks * 64 + g * 16));
        st[t] = mfma_16x16x32_bf16(aK, qf[ks], st[t]);
      }
    }
    __builtin_amdgcn_s_setprio(0);

    // ---- log2-domain online softmax (lane-scalar: this lane's q = lr)
    float s[4][4];
    float mx = -INFINITY;
#pragma unroll
    for (int t = 0; t < 4; ++t) {
      const float bb[4] = {b4[t].x, b4[t].y, b4[t].z, b4[t].w};
#pragma unroll
      for (int r = 0; r < 4; ++r) s[t][r] = fmaf(st[t][r], SCALE2, bb[r]);
      mx = fmaxf(mx, fmaxf(fmaxf(s[t][0], s[t][1]), fmaxf(s[t][2], s[t][3])));
    }
    mx = fmaxf(mx, __shfl_xor(mx, 16, 64));
    mx = fmaxf(mx, __shfl_xor(mx, 32, 64));

    // defer-max: only rescale when the row max grew by > THR2 (rare)
    if (__any(mx > m_i + THR2)) {
      const float mn   = fmaxf(m_i, mx);
      const float corr = exp2_fast(m_i - mn);  // exp2(-inf)=0 on first tile
      l_i *= corr;
#pragma unroll
      for (int c = 0; c < 4; ++c) acc[c] = acc[c] * corr;
      m_i = mn;
    }

    float rs = 0.f;
    v4s pb[4];
#pragma unroll
    for (int t = 0; t < 4; ++t) {
#pragma unroll
      for (int r = 0; r < 4; ++r) {
        float pv = exp2_fast(s[t][r] - m_i);  // bounded by 2^THR2 ~ 2980
        rs += pv;
        pb[t][r] = (short)f2bf(pv);
      }
    }
    rs += __shfl_xor(rs, 16, 64);
    rs += __shfl_xor(rs, 32, 64);
    l_i += rs;

    // ---- PV: O^T += V^T-chunk(16d x 16kv) @ P^T-chunk(16kv x 16q)
    __builtin_amdgcn_s_setprio(1);
#pragma unroll
    for (int t = 0; t < 4; ++t) {
#pragma unroll
      for (int c = 0; c < 4; ++c) {
        v4s aV = *reinterpret_cast<const v4s*>(
            Vs + swz(c * 16 + lr, t * 32 + g * 8));
        acc[c] = mfma_16x16x16_bf16(aV, pb[t], acc[c]);
      }
    }
    __builtin_amdgcn_s_setprio(0);

    __syncthreads();  // prefetch drained; all waves done reading buf[cur]
    cur ^= 1;
  }

  // ---- epilogue: O[q][d] = O^T/l, bf16 out
  const float inv = 1.0f / l_i;
  unsigned short* orow = og + ((size_t)b * S + q0 + wv * 16 + lr) * D + h * HD;
#pragma unroll
  for (int c = 0; c < 4; ++c) {
    float4 f = make_float4(acc[c][0] * inv, acc[c][1] * inv, acc[c][2] * inv,
                           acc[c][3] * inv);
    *reinterpret_cast<ushort4*>(orow + c * 16 + g * 4) = pack4(f);
  }
}

// ---------------------------------------------------------------------------
// Launch. ws layout (bf16 unless noted):
//   qx|kx|vx [B*S*D]  (converted inputs; qx reused as attn-out ab)
//   wqb|wkb|wvb|wob [D*D]   qb|kb [B*S*D]   vt [B*S*D]   sbias f32[B*S]
// ---------------------------------------------------------------------------
extern "C" void kernel_launch(void* const* d_in, const int* in_sizes, int n_in,
                              void* d_out, int out_size, void* d_ws,
                              size_t ws_size, hipStream_t stream) {
  const float* query = (const float*)d_in[0];
  const float* key_  = (const float*)d_in[1];
  const float* value = (const float*)d_in[2];
  const float* pos   = (const float*)d_in[3];
  const int*   amask = (const int*)d_in[4];
  const float* Wq = (const float*)d_in[5];
  const float* bq = (const float*)d_in[6];
  const float* Wk = (const float*)d_in[7];
  const float* bk = (const float*)d_in[8];
  const float* Wv = (const float*)d_in[9];
  const float* bv = (const float*)d_in[10];
  const float* Wo = (const float*)d_in[11];
  const float* bo = (const float*)d_in[12];
  float* out = (float*)d_out;

  constexpr size_t NBSD = (size_t)B * S * D;
  constexpr size_t NDD  = (size_t)D * D;
  unsigned short* qx  = (unsigned short*)d_ws;
  unsigned short* kx  = qx + NBSD;
  unsigned short* vx  = kx + NBSD;
  unsigned short* wqb = vx + NBSD;
  unsigned short* wkb = wqb + NDD;
  unsigned short* wvb = wkb + NDD;
  unsigned short* wob = wvb + NDD;
  unsigned short* qb  = wob + NDD;
  unsigned short* kb  = qb + NBSD;
  unsigned short* vt  = kb + NBSD;
  float* sbias_g = (float*)(vt + NBSD);
  unsigned short* ab = qx;  // reuse: qx dead after QKV projection

  CvtArgs ca;
  ca.src[0] = query; ca.dst[0] = qx;  ca.n[0] = (int)NBSD;
  ca.src[1] = key_;  ca.dst[1] = kx;  ca.n[1] = (int)NBSD;
  ca.src[2] = value; ca.dst[2] = vx;  ca.n[2] = (int)NBSD;
  ca.src[3] = Wq;    ca.dst[3] = wqb; ca.n[3] = (int)NDD;
  ca.src[4] = Wk;    ca.dst[4] = wkb; ca.n[4] = (int)NDD;
  ca.src[5] = Wv;    ca.dst[5] = wvb; ca.n[5] = (int)NDD;
  ca.src[6] = Wo;    ca.dst[6] = wob; ca.n[6] = (int)NDD;
  convert_kernel<<<dim3(2048, 7), 256, 0, stream>>>(ca);

  const int tail_elems = out_size - (int)NBSD;
  sink_kernel<<<B, 256, 0, stream>>>(pos, amask, sbias_g, out + NBSD,
                                     tail_elems);

  QKVArgs qa;
  qa.x[0] = qx; qa.w[0] = wqb; qa.bias[0] = bq; qa.y[0] = qb;
  qa.x[1] = kx; qa.w[1] = wkb; qa.bias[1] = bk; qa.y[1] = kb;
  qa.x[2] = vx; qa.w[2] = wvb; qa.bias[2] = bv; qa.y[2] = vt;
  gemm_qkv<<<768, 256, 0, stream>>>(qa);

  attn_kernel<<<1024, 256, 0, stream>>>(qb, kb, vt, sbias_g, ab);

  gemm_o<<<dim3(D / 64, (B * S) / 128), 256, 0, stream>>>(ab, wob, bo, out);
}

// Round 13
// 254.943 us; speedup vs baseline: 8.1545x; 1.0215x over previous
//
#include <hip/hip_runtime.h>
#include <hip/hip_bf16.h>
#include <math.h>

// Problem constants (fixed instance: B=2, S=2048, D=1024, H=16)
constexpr int B  = 2;
constexpr int S  = 2048;
constexpr int D  = 1024;
constexpr int H  = 16;
constexpr int HD = 64;
constexpr float SINK_STRENGTH = 0.1f;
constexpr float LOG2E  = 1.4426950408889634f;
constexpr float SCALE2 = 0.125f * LOG2E;       // score scale in log2 domain
constexpr float THR2   = 8.0f * LOG2E;         // defer-max threshold (T13)

typedef short v4s __attribute__((ext_vector_type(4)));
typedef short v8s __attribute__((ext_vector_type(8)));
typedef float v4f __attribute__((ext_vector_type(4)));

// exp2 via v_exp_f32 (D = 2^S0). __exp2f is NOT a device function on this
// toolchain (glibc macro collision, round-10 compile failure).
__device__ inline float exp2_fast(float x) {
  return __builtin_amdgcn_exp2f(x);
}

__device__ inline v4f mfma_16x16x32_bf16(v8s a, v8s b, v4f c) {
  return __builtin_amdgcn_mfma_f32_16x16x32_bf16(a, b, c, 0, 0, 0);
}

__device__ inline v4f mfma_16x16x16_bf16(v4s a, v4s b, v4f c) {
#if defined(__has_builtin)
#if __has_builtin(__builtin_amdgcn_mfma_f32_16x16x16bf16_1k)
  return __builtin_amdgcn_mfma_f32_16x16x16bf16_1k(a, b, c, 0, 0, 0);
#define MFMA16_DONE 1
#endif
#endif
#ifndef MFMA16_DONE
  v4f d;
  asm volatile("v_mfma_f32_16x16x16_bf16 %0, %1, %2, %3"
               : "=v"(d) : "v"(a), "v"(b), "v"(c));
  return d;
#endif
}

__device__ inline unsigned short f2bf(float f) {
  __hip_bfloat16 h = __float2bfloat16(f);  // RNE
  return *reinterpret_cast<unsigned short*>(&h);
}

__device__ inline ushort4 pack4(float4 f) {
  return make_ushort4(f2bf(f.x), f2bf(f.y), f2bf(f.z), f2bf(f.w));
}

// ---------------------------------------------------------------------------
// global_load_lds staging (rule 21: linear LDS dest, inverse-swizzled source,
// swizzled read). stage8 = 8 rows x 128B per wave call.
// ---------------------------------------------------------------------------
__device__ inline void gld16(const void* g, void* l) {
  __builtin_amdgcn_global_load_lds(
      (const __attribute__((address_space(1))) void*)g,
      (__attribute__((address_space(3))) void*)l, 16, 0, 0);
}

__device__ inline void stage8(const unsigned char* gbase, size_t gstride,
                              unsigned char* ldsbase, int rb, int lane) {
  const int r = rb + (lane >> 3);
  const int c = (lane & 7) * 16;
  const unsigned char* g = gbase + (size_t)r * gstride + (c ^ ((r & 7) << 4));
  gld16(g, ldsbase + rb * 128);
}

__device__ inline unsigned swz(int row, int bytecol) {
  return (unsigned)(row * 128 + (bytecol ^ ((row & 7) << 4)));
}

// ---------------------------------------------------------------------------
// Kernel 0: batched fp32 -> bf16 conversion (3 inputs + 4 weights).
// ---------------------------------------------------------------------------
struct CvtArgs {
  const float* src[7];
  unsigned short* dst[7];
  int n[7];
};

__global__ __launch_bounds__(256) void convert_kernel(CvtArgs a) {
  const int t = blockIdx.y;
  const float* s = a.src[t];
  unsigned short* d = a.dst[t];
  const int n = a.n[t];
  for (int i = (blockIdx.x * 256 + threadIdx.x) * 8; i < n;
       i += gridDim.x * 256 * 8) {
    float4 f0 = *reinterpret_cast<const float4*>(s + i);
    float4 f1 = *reinterpret_cast<const float4*>(s + i + 4);
    *reinterpret_cast<ushort4*>(d + i)     = pack4(f0);
    *reinterpret_cast<ushort4*>(d + i + 4) = pack4(f1);
  }
}

// ---------------------------------------------------------------------------
// Kernel 1: sink index (argmin over valid positions, first-tie) + merged
// per-key bias, PRE-SCALED by log2e.
// ---------------------------------------------------------------------------
__global__ void sink_kernel(const float* __restrict__ pos,
                            const int* __restrict__ mask,
                            float* __restrict__ sbias_g,
                            float* __restrict__ out_tail, int tail_elems) {
  const int b = blockIdx.x;
  __shared__ float sval[256];
  __shared__ int   sidx[256];
  float best = INFINITY;
  int   bidx = 0x7fffffff;
  for (int i = threadIdx.x; i < S; i += 256) {
    float v = (mask[b * S + i] == 0) ? INFINITY : pos[b * S + i];
    if (v < best || (v == best && i < bidx)) { best = v; bidx = i; }
  }
  sval[threadIdx.x] = best;
  sidx[threadIdx.x] = bidx;
  __syncthreads();
  for (int off = 128; off > 0; off >>= 1) {
    if ((int)threadIdx.x < off) {
      float v  = sval[threadIdx.x + off];
      int   ix = sidx[threadIdx.x + off];
      if (v < sval[threadIdx.x] ||
          (v == sval[threadIdx.x] && ix < sidx[threadIdx.x])) {
        sval[threadIdx.x] = v;
        sidx[threadIdx.x] = ix;
      }
    }
    __syncthreads();
  }
  const int sb = sidx[0];
  if (threadIdx.x == 0 && b < tail_elems) out_tail[b] = (float)sb;
  for (int i = threadIdx.x; i < S; i += 256)
    sbias_g[b * S + i] =
        (mask[b * S + i] ? ((i == sb) ? SINK_STRENGTH : 0.f) : -1e9f) * LOG2E;
}

// ---------------------------------------------------------------------------
// Kernel 2: FUSED Q/K/V projection GEMM. 128x128 tile, BK=64, 4 waves.
// Grid 768 (1D), XCD-chunked. z=2 (V) writes V^T bf16 [B][H][HD][S].
// ---------------------------------------------------------------------------
struct QKVArgs {
  const unsigned short* x[3];
  const unsigned short* w[3];
  const float* bias[3];
  unsigned short* y[3];
};

__global__ __launch_bounds__(256) void gemm_qkv(QKVArgs args) {
  __shared__ __align__(16) unsigned char lds[2 * 32768];  // (X 16K + W 16K) x2
  int id = blockIdx.x;
  id = (id & 7) * 96 + (id >> 3);  // XCD-chunked bijection (768 % 8 == 0)
  const int z = id >> 8, rem = id & 255;
  const int m0 = (rem >> 3) * 128, n0 = (rem & 7) * 128;

  const int tid = threadIdx.x, lane = tid & 63, w = tid >> 6;
  const int wr = w >> 1, wc = w & 1, lr = lane & 15, g = lane >> 4;
  const unsigned short* X  = args.x[z];
  const unsigned short* Wb = args.w[z];
  const unsigned char* xg = (const unsigned char*)(X + (size_t)m0 * D);
  const unsigned char* wg = (const unsigned char*)(Wb + (size_t)n0 * D);
  const size_t stride = (size_t)D * 2;

  auto stage = [&](int buf, int k0) {
    unsigned char* Xs = lds + buf * 32768;
    unsigned char* Ws = Xs + 16384;
    const unsigned char* xk = xg + (size_t)k0 * 2;
    const unsigned char* wk = wg + (size_t)k0 * 2;
#pragma unroll
    for (int u = 0; u < 4; ++u) stage8(xk, stride, Xs, w * 32 + u * 8, lane);
#pragma unroll
    for (int u = 0; u < 4; ++u) stage8(wk, stride, Ws, w * 32 + u * 8, lane);
  };

  stage(0, 0);
  v4f acc[4][4] = {};
  const int ksteps = D / 64;
  int cur = 0;
  for (int s = 0; s < ksteps; ++s) {
    __syncthreads();  // buf[cur] ready (vmcnt drained); prev reads done
    if (s + 1 < ksteps) stage(cur ^ 1, (s + 1) * 64);  // overlaps MFMA below
    const unsigned char* Xs = lds + cur * 32768;
    const unsigned char* Ws = Xs + 16384;
    const int sw = (lr & 7) << 4;
#pragma unroll
    for (int ks = 0; ks < 2; ++ks) {
      v8s a[4], bb[4];
#pragma unroll
      for (int mf = 0; mf < 4; ++mf)
        a[mf] = *reinterpret_cast<const v8s*>(
            Xs + (wr * 64 + mf * 16 + lr) * 128 + ((ks * 64 + g * 16) ^ sw));
#pragma unroll
      for (int nf = 0; nf < 4; ++nf)
        bb[nf] = *reinterpret_cast<const v8s*>(
            Ws + (wc * 64 + nf * 16 + lr) * 128 + ((ks * 64 + g * 16) ^ sw));
#pragma unroll
      for (int mf = 0; mf < 4; ++mf)
#pragma unroll
        for (int nf = 0; nf < 4; ++nf)
          acc[mf][nf] = mfma_16x16x32_bf16(a[mf], bb[nf], acc[mf][nf]);
    }
    cur ^= 1;
  }

  // epilogue: C/D layout col = lane&15 (n), row = g*4 + reg (m)
  const float* bias = args.bias[z];
  unsigned short* Y = args.y[z];
  if (z < 2) {  // Q, K: bf16 row-major [B*S, D]
#pragma unroll
    for (int nf = 0; nf < 4; ++nf) {
      const int n = n0 + wc * 64 + nf * 16 + lr;
      const float bs = bias[n];
#pragma unroll
      for (int mf = 0; mf < 4; ++mf)
#pragma unroll
        for (int r = 0; r < 4; ++r)
          Y[(size_t)(m0 + wr * 64 + mf * 16 + g * 4 + r) * D + n] =
              f2bf(acc[mf][nf][r] + bs);
    }
  } else {  // V: bf16 V^T [B][H][HD][S]
#pragma unroll
    for (int nf = 0; nf < 4; ++nf) {
      const int n = n0 + wc * 64 + nf * 16 + lr;
      const int hh = n >> 6, dd = n & 63;
      const float bs = bias[n];
#pragma unroll
      for (int mf = 0; mf < 4; ++mf) {
        const int m = m0 + wr * 64 + mf * 16 + g * 4;
        const int bb2 = m >> 11, ss = m & 2047;
        float4 f = make_float4(acc[mf][nf][0] + bs, acc[mf][nf][1] + bs,
                               acc[mf][nf][2] + bs, acc[mf][nf][3] + bs);
        *reinterpret_cast<ushort4*>(
            &Y[(((size_t)bb2 * H + hh) * HD + dd) * S + ss]) = pack4(f);
      }
    }
  }
}

// ---------------------------------------------------------------------------
// Kernel 3: O projection — 128x128 m97-density tile. Grid 256 (1D
// XCD-chunked), fp32 out.
// ---------------------------------------------------------------------------
__global__ __launch_bounds__(256) void gemm_o(
    const unsigned short* __restrict__ X, const unsigned short* __restrict__ Wb,
    const float* __restrict__ bias, float* __restrict__ Y) {
  __shared__ __align__(16) unsigned char lds[2 * 32768];
  int id = blockIdx.x;
  id = (id & 7) * 32 + (id >> 3);  // XCD-chunked bijection (256 % 8 == 0)
  const int m0 = (id >> 3) * 128, n0 = (id & 7) * 128;

  const int tid = threadIdx.x, lane = tid & 63, w = tid >> 6;
  const int wr = w >> 1, wc = w & 1, lr = lane & 15, g = lane >> 4;
  const unsigned char* xg = (const unsigned char*)(X + (size_t)m0 * D);
  const unsigned char* wg = (const unsigned char*)(Wb + (size_t)n0 * D);
  const size_t stride = (size_t)D * 2;

  auto stage = [&](int buf, int k0) {
    unsigned char* Xs = lds + buf * 32768;
    unsigned char* Ws = Xs + 16384;
    const unsigned char* xk = xg + (size_t)k0 * 2;
    const unsigned char* wk = wg + (size_t)k0 * 2;
#pragma unroll
    for (int u = 0; u < 4; ++u) stage8(xk, stride, Xs, w * 32 + u * 8, lane);
#pragma unroll
    for (int u = 0; u < 4; ++u) stage8(wk, stride, Ws, w * 32 + u * 8, lane);
  };

  stage(0, 0);
  v4f acc[4][4] = {};
  const int ksteps = D / 64;
  int cur = 0;
  for (int s = 0; s < ksteps; ++s) {
    __syncthreads();
    if (s + 1 < ksteps) stage(cur ^ 1, (s + 1) * 64);
    const unsigned char* Xs = lds + cur * 32768;
    const unsigned char* Ws = Xs + 16384;
    const int sw = (lr & 7) << 4;
#pragma unroll
    for (int ks = 0; ks < 2; ++ks) {
      v8s a[4], bb[4];
#pragma unroll
      for (int mf = 0; mf < 4; ++mf)
        a[mf] = *reinterpret_cast<const v8s*>(
            Xs + (wr * 64 + mf * 16 + lr) * 128 + ((ks * 64 + g * 16) ^ sw));
#pragma unroll
      for (int nf = 0; nf < 4; ++nf)
        bb[nf] = *reinterpret_cast<const v8s*>(
            Ws + (wc * 64 + nf * 16 + lr) * 128 + ((ks * 64 + g * 16) ^ sw));
#pragma unroll
      for (int mf = 0; mf < 4; ++mf)
#pragma unroll
        for (int nf = 0; nf < 4; ++nf)
          acc[mf][nf] = mfma_16x16x32_bf16(a[mf], bb[nf], acc[mf][nf]);
    }
    cur ^= 1;
  }

#pragma unroll
  for (int nf = 0; nf < 4; ++nf) {
    const int n = n0 + wc * 64 + nf * 16 + lr;
    const float bs = bias[n];
#pragma unroll
    for (int mf = 0; mf < 4; ++mf)
#pragma unroll
      for (int r = 0; r < 4; ++r)
        Y[(size_t)(m0 + wr * 64 + mf * 16 + g * 4 + r) * D + n] =
            acc[mf][nf][r] + bs;
  }
}

// ---------------------------------------------------------------------------
// Kernel 4: flash attention, BQ=128 (2 q-strips/wave): each K/V ds_read
// feeds 2 MFMAs; staging/barriers amortize 2x. l computed via ones-MFMA
// (layout-proof all-ones A-fragment -> column sums of P on the MFMA pipe).
// Grid 512, XCD-chunked.
// ---------------------------------------------------------------------------
__global__ __launch_bounds__(256) void attn_kernel(
    const unsigned short* __restrict__ qg, const unsigned short* __restrict__ kg,
    const unsigned short* __restrict__ vt, const float* __restrict__ sbias_g,
    unsigned short* __restrict__ og) {
  __shared__ __align__(16) unsigned char smem[16384 + 2 * 16384];  // Q | (K,V)x2
  int id = blockIdx.x;
  id = (id & 7) * 64 + (id >> 3);  // XCD-chunked bijection (512 % 8 == 0)
  const int q0 = (id & 15) * 128, hb = id >> 4;  // 4 (b,h) groups per XCD
  const int h = hb & 15, b = hb >> 4;

  const int tid = threadIdx.x, lane = tid & 63, wv = tid >> 6;
  const int lr = lane & 15, g = lane >> 4;

  const unsigned char* qgb =
      (const unsigned char*)(qg + ((size_t)b * S + q0) * D + h * HD);
  const unsigned char* kgb0 =
      (const unsigned char*)(kg + (size_t)b * S * D + h * HD);
  const unsigned char* vtb =
      (const unsigned char*)(vt + ((size_t)b * H + h) * HD * S);

  // prologue: stage Q (128 rows) and K/V tile 0, drain, hoist Q fragments
#pragma unroll
  for (int u = 0; u < 4; ++u) stage8(qgb, D * 2, smem, wv * 32 + u * 8, lane);
  {
    unsigned char* Ks = smem + 16384;
    unsigned char* Vs = Ks + 8192;
    stage8(kgb0, D * 2, Ks, wv * 16, lane);
    stage8(kgb0, D * 2, Ks, wv * 16 + 8, lane);
    stage8(vtb, S * 2, Vs, wv * 16, lane);
    stage8(vtb, S * 2, Vs, wv * 16 + 8, lane);
  }
  __syncthreads();
  v8s qf0[2], qf1[2];
#pragma unroll
  for (int ks = 0; ks < 2; ++ks) {
    qf0[ks] = *reinterpret_cast<const v8s*>(
        smem + swz(wv * 16 + lr, ks * 64 + g * 16));
    qf1[ks] = *reinterpret_cast<const v8s*>(
        smem + swz(64 + wv * 16 + lr, ks * 64 + g * 16));
  }

  const v4s vones = {(short)0x3F80, (short)0x3F80, (short)0x3F80,
                     (short)0x3F80};  // bf16 1.0 x4
  float m0_ = -INFINITY, m1_ = -INFINITY;  // running max, log2 domain
  v4f acc0[4] = {}, acc1[4] = {};
  v4f accl0 = {}, accl1 = {};  // l accumulators (all 4 regs equal)
  float4 b4[4];
  int cur = 0;

  // softmax for one strip: scale+bias, max-reduce, defer-max rescale, P pack
  auto softmax_strip = [&](v4f (&st)[4], float& m_, v4f (&acc)[4], v4f& accl,
                           v4s (&pb)[4]) {
    float s[4][4];
    float mx = -INFINITY;
#pragma unroll
    for (int t = 0; t < 4; ++t) {
      const float bbv[4] = {b4[t].x, b4[t].y, b4[t].z, b4[t].w};
#pragma unroll
      for (int r = 0; r < 4; ++r) s[t][r] = fmaf(st[t][r], SCALE2, bbv[r]);
      mx = fmaxf(fmaxf(mx, fmaxf(s[t][0], s[t][1])),
                 fmaxf(s[t][2], s[t][3]));
    }
    mx = fmaxf(mx, __shfl_xor(mx, 16, 64));
    mx = fmaxf(mx, __shfl_xor(mx, 32, 64));
    if (__any(mx > m_ + THR2)) {  // rare after first tile (T13)
      const float mn   = fmaxf(m_, mx);
      const float corr = exp2_fast(m_ - mn);  // exp2(-inf)=0 on first tile
#pragma unroll
      for (int c = 0; c < 4; ++c) acc[c] = acc[c] * corr;
      accl = accl * corr;
      m_ = mn;
    }
#pragma unroll
    for (int t = 0; t < 4; ++t)
#pragma unroll
      for (int r = 0; r < 4; ++r)
        pb[t][r] = (short)f2bf(exp2_fast(s[t][r] - m_));  // <= 2^THR2
  };

  for (int kv0 = 0; kv0 < S; kv0 += 64) {
    const unsigned char* Ks = smem + 16384 + cur * 16384;
    const unsigned char* Vs = Ks + 8192;

    // sbias loads FIRST (older than stage glds -> their wait doesn't drain
    // the prefetch queue)
#pragma unroll
    for (int t = 0; t < 4; ++t)
      b4[t] = *reinterpret_cast<const float4*>(
          &sbias_g[b * S + kv0 + t * 16 + g * 4]);

    // prefetch next K/V tile (async, overlaps all compute below)
    if (kv0 + 64 < S) {
      unsigned char* Kn = smem + 16384 + (cur ^ 1) * 16384;
      unsigned char* Vn = Kn + 8192;
      const unsigned char* kgb = kgb0 + (size_t)(kv0 + 64) * (D * 2);
      const unsigned char* vgb = vtb + (size_t)(kv0 + 64) * 2;
      stage8(kgb, D * 2, Kn, wv * 16, lane);
      stage8(kgb, D * 2, Kn, wv * 16 + 8, lane);
      stage8(vgb, S * 2, Vn, wv * 16, lane);
      stage8(vgb, S * 2, Vn, wv * 16 + 8, lane);
    }

    // ---- QK^T both strips: each aK read feeds 2 MFMAs
    v4f st0[4] = {}, st1[4] = {};
    __builtin_amdgcn_s_setprio(1);
#pragma unroll
    for (int t = 0; t < 4; ++t) {
#pragma unroll
      for (int ks = 0; ks < 2; ++ks) {
        v8s aK = *reinterpret_cast<const v8s*>(
            Ks + swz(t * 16 + lr, ks * 64 + g * 16));
        st0[t] = mfma_16x16x32_bf16(aK, qf0[ks], st0[t]);
        st1[t] = mfma_16x16x32_bf16(aK, qf1[ks], st1[t]);
      }
    }
    __builtin_amdgcn_s_setprio(0);

    // ---- softmax per strip (independent chains -> ILP)
    v4s pb0[4], pb1[4];
    softmax_strip(st0, m0_, acc0, accl0, pb0);
    softmax_strip(st1, m1_, acc1, accl1, pb1);

    // ---- PV both strips: each aV read feeds 2 MFMAs; l via ones-MFMA
    __builtin_amdgcn_s_setprio(1);
#pragma unroll
    for (int t = 0; t < 4; ++t) {
      accl0 = mfma_16x16x16_bf16(vones, pb0[t], accl0);
      accl1 = mfma_16x16x16_bf16(vones, pb1[t], accl1);
#pragma unroll
      for (int c = 0; c < 4; ++c) {
        v4s aV = *reinterpret_cast<const v4s*>(
            Vs + swz(c * 16 + lr, t * 32 + g * 8));
        acc0[c] = mfma_16x16x16_bf16(aV, pb0[t], acc0[c]);
        acc1[c] = mfma_16x16x16_bf16(aV, pb1[t], acc1[c]);
      }
    }
    __builtin_amdgcn_s_setprio(0);

    __syncthreads();  // prefetch drained; all waves done reading buf[cur]
    cur ^= 1;
  }

  // ---- epilogue: O[q][d] = O^T/l, bf16 out (both strips)
  const float inv0 = 1.0f / accl0[0];
  const float inv1 = 1.0f / accl1[0];
  unsigned short* o0 =
      og + ((size_t)b * S + q0 + wv * 16 + lr) * D + h * HD;
  unsigned short* o1 =
      og + ((size_t)b * S + q0 + 64 + wv * 16 + lr) * D + h * HD;
#pragma unroll
  for (int c = 0; c < 4; ++c) {
    float4 f0 = make_float4(acc0[c][0] * inv0, acc0[c][1] * inv0,
                            acc0[c][2] * inv0, acc0[c][3] * inv0);
    float4 f1 = make_float4(acc1[c][0] * inv1, acc1[c][1] * inv1,
                            acc1[c][2] * inv1, acc1[c][3] * inv1);
    *reinterpret_cast<ushort4*>(o0 + c * 16 + g * 4) = pack4(f0);
    *reinterpret_cast<ushort4*>(o1 + c * 16 + g * 4) = pack4(f1);
  }
}

// ---------------------------------------------------------------------------
// Launch. ws layout (bf16 unless noted):
//   qx|kx|vx [B*S*D]  (converted inputs; qx reused as attn-out ab)
//   wqb|wkb|wvb|wob [D*D]   qb|kb [B*S*D]   vt [B*S*D]   sbias f32[B*S]
// ---------------------------------------------------------------------------
extern "C" void kernel_launch(void* const* d_in, const int* in_sizes, int n_in,
                              void* d_out, int out_size, void* d_ws,
                              size_t ws_size, hipStream_t stream) {
  const float* query = (const float*)d_in[0];
  const float* key_  = (const float*)d_in[1];
  const float* value = (const float*)d_in[2];
  const float* pos   = (const float*)d_in[3];
  const int*   amask = (const int*)d_in[4];
  const float* Wq = (const float*)d_in[5];
  const float* bq = (const float*)d_in[6];
  const float* Wk = (const float*)d_in[7];
  const float* bk = (const float*)d_in[8];
  const float* Wv = (const float*)d_in[9];
  const float* bv = (const float*)d_in[10];
  const float* Wo = (const float*)d_in[11];
  const float* bo = (const float*)d_in[12];
  float* out = (float*)d_out;

  constexpr size_t NBSD = (size_t)B * S * D;
  constexpr size_t NDD  = (size_t)D * D;
  unsigned short* qx  = (unsigned short*)d_ws;
  unsigned short* kx  = qx + NBSD;
  unsigned short* vx  = kx + NBSD;
  unsigned short* wqb = vx + NBSD;
  unsigned short* wkb = wqb + NDD;
  unsigned short* wvb = wkb + NDD;
  unsigned short* wob = wvb + NDD;
  unsigned short* qb  = wob + NDD;
  unsigned short* kb  = qb + NBSD;
  unsigned short* vt  = kb + NBSD;
  float* sbias_g = (float*)(vt + NBSD);
  unsigned short* ab = qx;  // reuse: qx dead after QKV projection

  CvtArgs ca;
  ca.src[0] = query; ca.dst[0] = qx;  ca.n[0] = (int)NBSD;
  ca.src[1] = key_;  ca.dst[1] = kx;  ca.n[1] = (int)NBSD;
  ca.src[2] = value; ca.dst[2] = vx;  ca.n[2] = (int)NBSD;
  ca.src[3] = Wq;    ca.dst[3] = wqb; ca.n[3] = (int)NDD;
  ca.src[4] = Wk;    ca.dst[4] = wkb; ca.n[4] = (int)NDD;
  ca.src[5] = Wv;    ca.dst[5] = wvb; ca.n[5] = (int)NDD;
  ca.src[6] = Wo;    ca.dst[6] = wob; ca.n[6] = (int)NDD;
  convert_kernel<<<dim3(2048, 7), 256, 0, stream>>>(ca);

  const int tail_elems = out_size - (int)NBSD;
  sink_kernel<<<B, 256, 0, stream>>>(pos, amask, sbias_g, out + NBSD,
                                     tail_elems);

  QKVArgs qa;
  qa.x[0] = qx; qa.w[0] = wqb; qa.bias[0] = bq; qa.y[0] = qb;
  qa.x[1] = kx; qa.w[1] = wkb; qa.bias[1] = bk; qa.y[1] = kb;
  qa.x[2] = vx; qa.w[2] = wvb; qa.bias[2] = bv; qa.y[2] = vt;
  gemm_qkv<<<768, 256, 0, stream>>>(qa);

  attn_kernel<<<512, 256, 0, stream>>>(qb, kb, vt, sbias_g, ab);

  gemm_o<<<256, 256, 0, stream>>>(ab, wob, bo, out);
}